// Round 1
// baseline (910.811 us; speedup 1.0000x reference)
//
#include <hip/hip_runtime.h>
#include <cfloat>
#include <cstdint>

#define B_  64
#define T_  1024
#define D_  128
#define NE  512            // clip limit; emb has NE+1 = 513 rows
#define P_  (B_*T_)        // 65536 positions

// d_out flat offsets (float32), in reference return order
#define O_KH   0
#define O_ENC  (P_*D_)             // 8388608
#define O_V    (O_ENC + P_)        // 8454144
#define O_LH   (O_V + 1)           // 8454145
#define O_LN   (O_LH + P_)         // 8519681
#define O_EM   (O_LN + P_)         // 8585217
#define O_LED  (O_EM + 1)          // 8585218

// ---------------------------------------------------------------------------
// Kernel A: per position p (64 per block), per n-chunk c (64 n's per wave,
// chunks {w, w+4} per wave) compute S[n] = ||emb_n||^2 - 2*ks_p.emb_n,
// emit: stay-bit ballot word, chunk-argmin partial, boundary S values.
// emb row chunk in VGPRs, ks via wave-uniform (scalar) loads.
// ---------------------------------------------------------------------------
__global__ __launch_bounds__(256) void kA(const float* __restrict__ ks,
                                          const float* __restrict__ emb,
                                          unsigned long long* __restrict__ bits,
                                          float* __restrict__ sfirst,
                                          float* __restrict__ slast,
                                          float* __restrict__ minv,
                                          int* __restrict__ mini)
{
    const int lane = threadIdx.x & 63;
    const int wv   = threadIdx.x >> 6;
    const int p0   = blockIdx.x * 64;

    for (int ci = 0; ci < 2; ci++) {
        const int c = wv + 4 * ci;          // chunk 0..7
        const int n = (c << 6) + lane;      // 0..511
        const float4* erow = (const float4*)(emb + (size_t)n * D_);

        // ||emb_n||^2
        float sq = 0.f;
        #pragma unroll
        for (int i = 0; i < 32; i++) {
            float4 e = erow[i];
            sq += e.x*e.x + e.y*e.y + e.z*e.z + e.w*e.w;
        }

        for (int pc = 0; pc < 2; pc++) {    // 2 passes of 32 positions
            float acc[32];
            #pragma unroll
            for (int i = 0; i < 32; i++) acc[i] = 0.f;

            for (int kc = 0; kc < 4; kc++) {
                float4 E[8];                // emb[n][kc*32 .. kc*32+31]
                #pragma unroll
                for (int i = 0; i < 8; i++) E[i] = erow[kc*8 + i];
                #pragma unroll
                for (int pp = 0; pp < 32; pp++) {
                    const float* krow = ks + (size_t)(p0 + pc*32 + pp) * D_ + kc*32;
                    float a = acc[pp];
                    #pragma unroll
                    for (int i = 0; i < 8; i++) {
                        a = fmaf(E[i].x, krow[4*i+0], a);
                        a = fmaf(E[i].y, krow[4*i+1], a);
                        a = fmaf(E[i].z, krow[4*i+2], a);
                        a = fmaf(E[i].w, krow[4*i+3], a);
                    }
                    acc[pp] = a;
                }
            }

            #pragma unroll
            for (int pp = 0; pp < 32; pp++) {
                const int p = p0 + pc*32 + pp;
                const float S = fmaf(-2.f, acc[pp], sq);
                const float Snxt = __shfl_down(S, 1);
                const unsigned long long w = __ballot(S <= Snxt); // bit63 garbage, patched in kB

                // argmin with first-index tie-break
                float mv = S; int mi = n;
                #pragma unroll
                for (int m = 32; m >= 1; m >>= 1) {
                    float v2 = __shfl_xor(mv, m);
                    int   i2 = __shfl_xor(mi, m);
                    if (v2 < mv || (v2 == mv && i2 < mi)) { mv = v2; mi = i2; }
                }
                if (lane == 0) {
                    bits  [(size_t)p*8 + c] = w;
                    sfirst[(size_t)p*8 + c] = S;
                    minv  [(size_t)p*8 + c] = mv;
                    mini  [(size_t)p*8 + c] = mi;
                }
                if (lane == 63) slast[(size_t)p*8 + c] = S;
            }
        }
    }
}

// ---------------------------------------------------------------------------
// Kernel B: one wave per b. Patch chunk-boundary stay bits, compute ind0
// (global argmin at t=0, clipped, masked), then speculative wave scan:
// lane j preloads the 2 bit-words covering [cur0, cur0+63] for t0+j; 64
// steps resolved via uniform readlane broadcasts.
// ---------------------------------------------------------------------------
__global__ __launch_bounds__(64) void kB(const float* __restrict__ ks,
                                         const float* __restrict__ emb,
                                         const unsigned char* __restrict__ mask,
                                         const unsigned long long* __restrict__ bits,
                                         const float* __restrict__ sfirst,
                                         const float* __restrict__ slast,
                                         const float* __restrict__ minv,
                                         const int* __restrict__ mini,
                                         int* __restrict__ enci,
                                         float* __restrict__ out)
{
    __shared__ unsigned long long lb[T_ * 8];   // 64 KB
    const int b    = blockIdx.x;
    const int lane = threadIdx.x;

    for (int i = lane; i < T_*8; i += 64) {
        const int t = i >> 3, c = i & 7;
        const size_t p = (size_t)b*T_ + t;
        unsigned long long w = bits[p*8 + c] & 0x7fffffffffffffffULL;
        bool stay63 = (c < 7) ? (slast[p*8 + c] <= sfirst[p*8 + c + 1]) : true;
        if (stay63) w |= 0x8000000000000000ULL;
        lb[i] = w;
    }
    __syncthreads();

    // ind0 from t=0: combine 8 chunk partials + S[512]
    const size_t p0 = (size_t)b * T_;
    {
        const float2 e = ((const float2*)(emb + (size_t)512*D_))[lane];
        const float2 k = ((const float2*)(ks  + p0*D_))[lane];
        float s5 = e.x*(e.x - 2.f*k.x) + e.y*(e.y - 2.f*k.y);
        #pragma unroll
        for (int m = 32; m >= 1; m >>= 1) s5 += __shfl_xor(s5, m);

        float mv; int mi;
        if (lane < 8)       { mv = minv[p0*8 + lane]; mi = mini[p0*8 + lane]; }
        else if (lane == 8) { mv = s5; mi = 512; }
        else                { mv = FLT_MAX; mi = 0x7fffffff; }
        #pragma unroll
        for (int m = 32; m >= 1; m >>= 1) {
            float v2 = __shfl_xor(mv, m);
            int   i2 = __shfl_xor(mi, m);
            if (v2 < mv || (v2 == mv && i2 < mi)) { mv = v2; mi = i2; }
        }
        int cur = (mi < NE) ? mi : NE - 1;
        if (mask[b]) cur = 0;
        if (lane == 0) { enci[p0] = cur; out[O_ENC + p0] = (float)cur; }

        // speculative scan over t = 1..1023
        for (int t0 = 1; t0 < T_; t0 += 64) {
            const int w0 = cur >> 6;
            const int w1 = (w0 < 7) ? w0 + 1 : 7;
            const int t  = t0 + lane;
            unsigned long long u0 = 0, u1 = 0;
            if (t < T_) { u0 = lb[t*8 + w0]; u1 = lb[t*8 + w1]; }
            const int base = w0 << 6;
            int myenc = cur;
            const int nst = (T_ - t0 < 64) ? (T_ - t0) : 64;
            for (int j = 0; j < nst; j++) {
                const unsigned long long a0 = __shfl(u0, j);
                const unsigned long long a1 = __shfl(u1, j);
                const int off = cur - base;                    // 0..126
                const int bit = (off < 64) ? (int)((a0 >> off) & 1ULL)
                                           : (int)((a1 >> (off - 64)) & 1ULL);
                cur += 1 - bit;
                if (lane == j) myenc = cur;
            }
            if (t < T_) { enci[p0 + t] = myenc; out[O_ENC + p0 + t] = (float)myenc; }
        }
    }
}

// ---------------------------------------------------------------------------
// Kernel C: one wave per position. Recompute S at {enc, enc+1, 512, argmin}
// via wave dot-products; emit key_hard, loss_here, loss_next, energy.
// ---------------------------------------------------------------------------
__global__ __launch_bounds__(256) void kC(const float* __restrict__ ks,
                                          const float* __restrict__ emb,
                                          const int* __restrict__ enci,
                                          const float* __restrict__ minv,
                                          const int* __restrict__ mini,
                                          float* __restrict__ out,
                                          float* __restrict__ energy)
{
    const int lane = threadIdx.x & 63;
    const size_t p = (size_t)blockIdx.x * 4 + (threadIdx.x >> 6);

    const float2 k  = ((const float2*)(ks + p*D_))[lane];
    const int eh = enci[p];
    const int en = (eh + 1 < NE) ? eh + 1 : NE - 1;
    const float2 Eh = ((const float2*)(emb + (size_t)eh*D_))[lane];
    const float2 En = ((const float2*)(emb + (size_t)en*D_))[lane];
    const float2 E5 = ((const float2*)(emb + (size_t)512*D_))[lane];

    float ph  = Eh.x*(Eh.x - 2.f*k.x) + Eh.y*(Eh.y - 2.f*k.y);
    float pn  = En.x*(En.x - 2.f*k.x) + En.y*(En.y - 2.f*k.y);
    float p5  = E5.x*(E5.x - 2.f*k.x) + E5.y*(E5.y - 2.f*k.y);
    float sqk = k.x*k.x + k.y*k.y;
    #pragma unroll
    for (int m = 32; m >= 1; m >>= 1) {
        ph  += __shfl_xor(ph, m);
        pn  += __shfl_xor(pn, m);
        p5  += __shfl_xor(p5, m);
        sqk += __shfl_xor(sqk, m);
    }

    // global argmin: 8 chunk partials + (S512, 512)
    float mv; int mi;
    if (lane < 8)       { mv = minv[p*8 + lane]; mi = mini[p*8 + lane]; }
    else if (lane == 8) { mv = p5; mi = 512; }
    else                { mv = FLT_MAX; mi = 0x7fffffff; }
    #pragma unroll
    for (int m = 32; m >= 1; m >>= 1) {
        float v2 = __shfl_xor(mv, m);
        int   i2 = __shfl_xor(mi, m);
        if (v2 < mv || (v2 == mv && i2 < mi)) { mv = v2; mi = i2; }
    }

    const float2 Em = ((const float2*)(emb + (size_t)mi*D_))[lane];
    float pm = Em.x*(Em.x - 2.f*k.x) + Em.y*(Em.y - 2.f*k.y);
    #pragma unroll
    for (int m = 32; m >= 1; m >>= 1) pm += __shfl_xor(pm, m);

    const float lh = 1.2f * (sqk + ph);
    const float ln = 1.2f * (sqk + pn);
    const float lm = 1.2f * (sqk + pm);
    // identical-formula S values => equal indices compare exactly equal (cond false)
    const float lossh = lh - ln - ((pm < ph) ? lm : 0.f);
    const float lossn = ln - lh - ((pm < pn) ? lm : 0.f);

    // straight-through: ks + (emb[enc] - ks), fp32 like the reference
    float2 kh;
    kh.x = k.x + (Eh.x - k.x);   // note: k here is post-reduction... recompute below
    kh.y = k.y + (Eh.y - k.y);
    // k was clobbered only in sqk path? no: sqk reduced separately; k intact.
    ((float2*)(out + p*D_))[lane] = kh;

    if (lane == 0) {
        out[O_LH + p] = lossh;
        out[O_LN + p] = lossn;
        energy[p] = 1.2f * (pn - ph);
    }
}

// ---------------------------------------------------------------------------
// Kernel D: scalar reductions (energy_mean, loss_energy_descent, v)
// ---------------------------------------------------------------------------
__global__ __launch_bounds__(256) void kD(const float* __restrict__ energy,
                                          const int* __restrict__ enci,
                                          float* __restrict__ out)
{
    __shared__ double sA[256], sB2[256];
    __shared__ int sV[64];
    double se = 0.0, sl = 0.0;
    const float eps = (float)(1e-6 / 512.0);
    for (int p = threadIdx.x; p < P_; p += 256) {
        const float e = energy[p];
        se += (double)e;
        if ((p & (T_-1)) < T_-1) {
            const float ec = (enci[p+1] == enci[p]) ? (energy[p+1] - energy[p]) : 0.f;
            sl += (double)fmaxf(ec + eps, 0.f);
        }
    }
    sA[threadIdx.x] = se; sB2[threadIdx.x] = sl;
    if (threadIdx.x < 64) {
        const int b = threadIdx.x;
        sV[b] = enci[b*T_ + T_-1] - enci[b*T_];   // enc is monotone in t
    }
    __syncthreads();
    for (int s = 128; s >= 1; s >>= 1) {
        if (threadIdx.x < (unsigned)s) { sA[threadIdx.x] += sA[threadIdx.x+s]; sB2[threadIdx.x] += sB2[threadIdx.x+s]; }
        __syncthreads();
    }
    if (threadIdx.x == 0) {
        int vmax = sV[0];
        for (int i = 1; i < 64; i++) vmax = (sV[i] > vmax) ? sV[i] : vmax;
        out[O_EM]  = (float)(sA[0] / (double)P_);
        out[O_LED] = (float)(sB2[0] / (double)(B_*(T_-1)));
        out[O_V]   = (float)vmax;
    }
}

// ---------------------------------------------------------------------------
extern "C" void kernel_launch(void* const* d_in, const int* in_sizes, int n_in,
                              void* d_out, int out_size, void* d_ws, size_t ws_size,
                              hipStream_t stream)
{
    const float* ks  = (const float*)d_in[0];
    const float* emb = (const float*)d_in[1];
    const unsigned char* mask = (const unsigned char*)d_in[2]; // all-zero bools either layout

    float* out = (float*)d_out;
    char* w = (char*)d_ws;
    unsigned long long* bits = (unsigned long long*)(w);                      // 4 MB
    float* sfirst = (float*)(w + (size_t) 4*1024*1024);                       // 2 MB
    float* slast  = (float*)(w + (size_t) 6*1024*1024);                       // 2 MB
    float* minv   = (float*)(w + (size_t) 8*1024*1024);                       // 2 MB
    int*   mini   = (int*)  (w + (size_t)10*1024*1024);                       // 2 MB
    int*   enci   = (int*)  (w + (size_t)12*1024*1024);                       // 256 KB
    float* energy = (float*)(w + (size_t)12*1024*1024 + 256*1024);            // 256 KB

    kA<<<P_/64, 256, 0, stream>>>(ks, emb, bits, sfirst, slast, minv, mini);
    kB<<<B_,    64,  0, stream>>>(ks, emb, mask, bits, sfirst, slast, minv, mini, enci, out);
    kC<<<P_/4,  256, 0, stream>>>(ks, emb, enci, minv, mini, out, energy);
    kD<<<1,     256, 0, stream>>>(energy, enci, out);
}

// Round 2
// 506.529 us; speedup vs baseline: 1.7981x; 1.7981x over previous
//
#include <hip/hip_runtime.h>
#include <cfloat>
#include <cstdint>

#define B_  64
#define T_  1024
#define D_  128
#define NE  512            // clip limit; emb has NE+1 = 513 rows
#define P_  (B_*T_)        // 65536 positions

// d_out flat offsets (float32), in reference return order
#define O_KH   0
#define O_ENC  (P_*D_)             // 8388608
#define O_V    (O_ENC + P_)        // 8454144
#define O_LH   (O_V + 1)           // 8454145
#define O_LN   (O_LH + P_)         // 8519681
#define O_EM   (O_LN + P_)         // 8585217
#define O_LED  (O_EM + 1)          // 8585218

// ---------------------------------------------------------------------------
// kE: sq[n] = ||emb_n||^2 for n = 0..512 (wave per row)
// ---------------------------------------------------------------------------
__global__ __launch_bounds__(256) void kE(const float* __restrict__ emb,
                                          float* __restrict__ sq)
{
    const int w = threadIdx.x >> 6, lane = threadIdx.x & 63;
    const int r = blockIdx.x * 4 + w;
    if (r > 512) return;
    const float2 e = ((const float2*)(emb + (size_t)r * D_))[lane];
    float s = e.x*e.x + e.y*e.y;
    #pragma unroll
    for (int m = 32; m >= 1; m >>= 1) s += __shfl_xor(s, m);
    if (lane == 0) sq[r] = s;
}

// ---------------------------------------------------------------------------
// kA: LDS-tiled register-blocked fp32 GEMM computing S[p][n] = sq[n]-2*ks.emb
// for a 128p x 128n tile, then epilogue emits per-(p, 64-chunk) stay-bit
// ballot word, chunk argmin, and boundary S values (same interface as r1).
// Tile: A_lds[k][p] stride 136, B_lds[k][n] stride 132 (transposed staging,
// 2-way-free bank patterns, 16B-aligned b128 frag reads). 8x8 micro-tile.
// ---------------------------------------------------------------------------
__global__ __launch_bounds__(256, 2) void kA(const float* __restrict__ ks,
                                             const float* __restrict__ emb,
                                             const float* __restrict__ sq,
                                             unsigned long long* __restrict__ bits,
                                             float* __restrict__ sfirst,
                                             float* __restrict__ slast,
                                             float* __restrict__ minv,
                                             int* __restrict__ mini)
{
    __shared__ float sh[17152];            // 68608 B; LDS caps us at 2 blocks/CU
    float* Ald = sh;                       // [64][136] = 8704 floats
    float* Bld = sh + 64*136;              // [64][132] = 8448 floats

    const int tid = threadIdx.x;
    const int pt  = tid & 15;              // p-frag: p = pt*8 .. pt*8+7
    const int nt  = tid >> 4;              // n-frag: n = nt*8 .. nt*8+7
    const int bp  = blockIdx.x >> 2;
    const int bn  = blockIdx.x & 3;
    const int p0  = bp * 128;
    const int n0  = bn * 128;

    const int sp  = tid >> 1;              // staging row 0..127
    const int shf = tid & 1;               // staging k-half (32 floats each)

    float acc[8][8];
    #pragma unroll
    for (int i = 0; i < 8; i++)
        #pragma unroll
        for (int j = 0; j < 8; j++) acc[i][j] = 0.f;

    const float* gA = ks  + (size_t)(p0+sp)*D_ + shf*32;
    const float* gB = emb + (size_t)(n0+sp)*D_ + shf*32;

    float4 vA[8], vB[8];

    auto stage = [&]() {
        #pragma unroll
        for (int i = 0; i < 8; i++) {
            const int k = shf*32 + i*4;
            Ald[(k+0)*136 + sp] = vA[i].x;
            Ald[(k+1)*136 + sp] = vA[i].y;
            Ald[(k+2)*136 + sp] = vA[i].z;
            Ald[(k+3)*136 + sp] = vA[i].w;
            Bld[(k+0)*132 + sp] = vB[i].x;
            Bld[(k+1)*132 + sp] = vB[i].y;
            Bld[(k+2)*132 + sp] = vB[i].z;
            Bld[(k+3)*132 + sp] = vB[i].w;
        }
    };
    const float* aP = Ald + pt*8;
    const float* bP = Bld + nt*8;
    auto kloop = [&]() {
        #pragma unroll 2
        for (int k = 0; k < 64; k++) {
            const float4 a0 = *(const float4*)(aP + k*136);
            const float4 a1 = *(const float4*)(aP + k*136 + 4);
            const float4 b0 = *(const float4*)(bP + k*132);
            const float4 b1 = *(const float4*)(bP + k*132 + 4);
            const float a[8] = {a0.x,a0.y,a0.z,a0.w,a1.x,a1.y,a1.z,a1.w};
            const float b[8] = {b0.x,b0.y,b0.z,b0.w,b1.x,b1.y,b1.z,b1.w};
            #pragma unroll
            for (int i = 0; i < 8; i++)
                #pragma unroll
                for (int j = 0; j < 8; j++)
                    acc[i][j] = fmaf(a[i], b[j], acc[i][j]);
        }
    };

    // pass 0 load + stage
    #pragma unroll
    for (int i = 0; i < 8; i++) vA[i] = ((const float4*)gA)[i];
    #pragma unroll
    for (int i = 0; i < 8; i++) vB[i] = ((const float4*)gB)[i];
    stage();
    __syncthreads();
    // prefetch pass 1 into registers (latency hidden by pass-0 compute)
    #pragma unroll
    for (int i = 0; i < 8; i++) vA[i] = ((const float4*)(gA + 64))[i];
    #pragma unroll
    for (int i = 0; i < 8; i++) vB[i] = ((const float4*)(gB + 64))[i];
    kloop();                               // pass 0
    __syncthreads();
    stage();
    __syncthreads();
    kloop();                               // pass 1

    // ---- epilogue ----
    float qv[8];
    {
        const float4 q0 = *(const float4*)(sq + n0 + nt*8);
        const float4 q1 = *(const float4*)(sq + n0 + nt*8 + 4);
        qv[0]=q0.x; qv[1]=q0.y; qv[2]=q0.z; qv[3]=q0.w;
        qv[4]=q1.x; qv[5]=q1.y; qv[6]=q1.z; qv[7]=q1.w;
    }
    __syncthreads();                       // done with A/B tiles
    float* Sld = sh;                       // [128][132] = 16896 <= 17152 floats
    #pragma unroll
    for (int i = 0; i < 8; i++) {
        float4 s0, s1;
        s0.x = fmaf(-2.f, acc[i][0], qv[0]);
        s0.y = fmaf(-2.f, acc[i][1], qv[1]);
        s0.z = fmaf(-2.f, acc[i][2], qv[2]);
        s0.w = fmaf(-2.f, acc[i][3], qv[3]);
        s1.x = fmaf(-2.f, acc[i][4], qv[4]);
        s1.y = fmaf(-2.f, acc[i][5], qv[5]);
        s1.z = fmaf(-2.f, acc[i][6], qv[6]);
        s1.w = fmaf(-2.f, acc[i][7], qv[7]);
        *(float4*)&Sld[(pt*8+i)*132 + nt*8]     = s0;
        *(float4*)&Sld[(pt*8+i)*132 + nt*8 + 4] = s1;
    }
    __syncthreads();

    const int lane = tid & 63;
    const int w    = tid >> 6;
    for (int idx = w; idx < 256; idx += 4) {   // 128 p x 2 chunks
        const int p = idx >> 1;
        const int c = idx & 1;
        const float S   = Sld[p*132 + c*64 + lane];
        const float Snx = __shfl_down(S, 1);
        const unsigned long long bw = __ballot(S <= Snx); // bit63 patched in kB
        float mv = S; int mi = n0 + c*64 + lane;
        #pragma unroll
        for (int m = 32; m >= 1; m >>= 1) {
            const float v2 = __shfl_xor(mv, m);
            const int   i2 = __shfl_xor(mi, m);
            if (v2 < mv || (v2 == mv && i2 < mi)) { mv = v2; mi = i2; }
        }
        const size_t pg = (size_t)(p0 + p);
        const int    cg = bn*2 + c;
        if (lane == 0) {
            bits  [pg*8 + cg] = bw;
            sfirst[pg*8 + cg] = S;
            minv  [pg*8 + cg] = mv;
            mini  [pg*8 + cg] = mi;
        }
        if (lane == 63) slast[pg*8 + cg] = S;
    }
}

// ---------------------------------------------------------------------------
// kB: one wave per b. Patch chunk-boundary stay bits, ind0 from global
// argmin at t=0, speculative 64-wide wave scan over t. (unchanged from r1)
// ---------------------------------------------------------------------------
__global__ __launch_bounds__(64) void kB(const float* __restrict__ ks,
                                         const float* __restrict__ emb,
                                         const unsigned char* __restrict__ mask,
                                         const unsigned long long* __restrict__ bits,
                                         const float* __restrict__ sfirst,
                                         const float* __restrict__ slast,
                                         const float* __restrict__ minv,
                                         const int* __restrict__ mini,
                                         int* __restrict__ enci,
                                         float* __restrict__ out)
{
    __shared__ unsigned long long lb[T_ * 8];   // 64 KB
    const int b    = blockIdx.x;
    const int lane = threadIdx.x;

    for (int i = lane; i < T_*8; i += 64) {
        const int t = i >> 3, c = i & 7;
        const size_t p = (size_t)b*T_ + t;
        unsigned long long w = bits[p*8 + c] & 0x7fffffffffffffffULL;
        bool stay63 = (c < 7) ? (slast[p*8 + c] <= sfirst[p*8 + c + 1]) : true;
        if (stay63) w |= 0x8000000000000000ULL;
        lb[i] = w;
    }
    __syncthreads();

    const size_t p0 = (size_t)b * T_;
    {
        const float2 e = ((const float2*)(emb + (size_t)512*D_))[lane];
        const float2 k = ((const float2*)(ks  + p0*D_))[lane];
        float s5 = e.x*(e.x - 2.f*k.x) + e.y*(e.y - 2.f*k.y);
        #pragma unroll
        for (int m = 32; m >= 1; m >>= 1) s5 += __shfl_xor(s5, m);

        float mv; int mi;
        if (lane < 8)       { mv = minv[p0*8 + lane]; mi = mini[p0*8 + lane]; }
        else if (lane == 8) { mv = s5; mi = 512; }
        else                { mv = FLT_MAX; mi = 0x7fffffff; }
        #pragma unroll
        for (int m = 32; m >= 1; m >>= 1) {
            float v2 = __shfl_xor(mv, m);
            int   i2 = __shfl_xor(mi, m);
            if (v2 < mv || (v2 == mv && i2 < mi)) { mv = v2; mi = i2; }
        }
        int cur = (mi < NE) ? mi : NE - 1;
        if (mask[b]) cur = 0;
        if (lane == 0) { enci[p0] = cur; out[O_ENC + p0] = (float)cur; }

        for (int t0 = 1; t0 < T_; t0 += 64) {
            const int w0 = cur >> 6;
            const int w1 = (w0 < 7) ? w0 + 1 : 7;
            const int t  = t0 + lane;
            unsigned long long u0 = 0, u1 = 0;
            if (t < T_) { u0 = lb[t*8 + w0]; u1 = lb[t*8 + w1]; }
            const int base = w0 << 6;
            int myenc = cur;
            const int nst = (T_ - t0 < 64) ? (T_ - t0) : 64;
            for (int j = 0; j < nst; j++) {
                const unsigned long long a0 = __shfl(u0, j);
                const unsigned long long a1 = __shfl(u1, j);
                const int off = cur - base;
                const int bit = (off < 64) ? (int)((a0 >> off) & 1ULL)
                                           : (int)((a1 >> (off - 64)) & 1ULL);
                cur += 1 - bit;
                if (lane == j) myenc = cur;
            }
            if (t < T_) { enci[p0 + t] = myenc; out[O_ENC + p0 + t] = (float)myenc; }
        }
    }
}

// ---------------------------------------------------------------------------
// kC: one wave per position. Recompute S at {enc, enc+1, 512, argmin} via
// wave dot-products; emit key_hard, loss_here, loss_next, energy. (r1)
// ---------------------------------------------------------------------------
__global__ __launch_bounds__(256) void kC(const float* __restrict__ ks,
                                          const float* __restrict__ emb,
                                          const int* __restrict__ enci,
                                          const float* __restrict__ minv,
                                          const int* __restrict__ mini,
                                          float* __restrict__ out,
                                          float* __restrict__ energy)
{
    const int lane = threadIdx.x & 63;
    const size_t p = (size_t)blockIdx.x * 4 + (threadIdx.x >> 6);

    const float2 k  = ((const float2*)(ks + p*D_))[lane];
    const int eh = enci[p];
    const int en = (eh + 1 < NE) ? eh + 1 : NE - 1;
    const float2 Eh = ((const float2*)(emb + (size_t)eh*D_))[lane];
    const float2 En = ((const float2*)(emb + (size_t)en*D_))[lane];
    const float2 E5 = ((const float2*)(emb + (size_t)512*D_))[lane];

    float ph  = Eh.x*(Eh.x - 2.f*k.x) + Eh.y*(Eh.y - 2.f*k.y);
    float pn  = En.x*(En.x - 2.f*k.x) + En.y*(En.y - 2.f*k.y);
    float p5  = E5.x*(E5.x - 2.f*k.x) + E5.y*(E5.y - 2.f*k.y);
    float sqk = k.x*k.x + k.y*k.y;
    #pragma unroll
    for (int m = 32; m >= 1; m >>= 1) {
        ph  += __shfl_xor(ph, m);
        pn  += __shfl_xor(pn, m);
        p5  += __shfl_xor(p5, m);
        sqk += __shfl_xor(sqk, m);
    }

    float mv; int mi;
    if (lane < 8)       { mv = minv[p*8 + lane]; mi = mini[p*8 + lane]; }
    else if (lane == 8) { mv = p5; mi = 512; }
    else                { mv = FLT_MAX; mi = 0x7fffffff; }
    #pragma unroll
    for (int m = 32; m >= 1; m >>= 1) {
        float v2 = __shfl_xor(mv, m);
        int   i2 = __shfl_xor(mi, m);
        if (v2 < mv || (v2 == mv && i2 < mi)) { mv = v2; mi = i2; }
    }

    const float2 Em = ((const float2*)(emb + (size_t)mi*D_))[lane];
    float pm = Em.x*(Em.x - 2.f*k.x) + Em.y*(Em.y - 2.f*k.y);
    #pragma unroll
    for (int m = 32; m >= 1; m >>= 1) pm += __shfl_xor(pm, m);

    const float lh = 1.2f * (sqk + ph);
    const float ln = 1.2f * (sqk + pn);
    const float lm = 1.2f * (sqk + pm);
    const float lossh = lh - ln - ((pm < ph) ? lm : 0.f);
    const float lossn = ln - lh - ((pm < pn) ? lm : 0.f);

    float2 kh;
    kh.x = k.x + (Eh.x - k.x);
    kh.y = k.y + (Eh.y - k.y);
    ((float2*)(out + p*D_))[lane] = kh;

    if (lane == 0) {
        out[O_LH + p] = lossh;
        out[O_LN + p] = lossn;
        energy[p] = 1.2f * (pn - ph);
    }
}

// ---------------------------------------------------------------------------
// kD1: per-256-position partial sums (energy, energy-descent terms)
// ---------------------------------------------------------------------------
__global__ __launch_bounds__(256) void kD1(const float* __restrict__ energy,
                                           const int* __restrict__ enci,
                                           double2* __restrict__ part)
{
    __shared__ double sA[256], sB[256];
    const int p = blockIdx.x * 256 + threadIdx.x;
    const float e = energy[p];
    double se = (double)e;
    double sl = 0.0;
    if ((p & (T_-1)) < T_-1) {
        const float ec = (enci[p+1] == enci[p]) ? (energy[p+1] - e) : 0.f;
        sl = (double)fmaxf(ec + (float)(1e-6/512.0), 0.f);
    }
    sA[threadIdx.x] = se; sB[threadIdx.x] = sl;
    __syncthreads();
    for (int s = 128; s >= 1; s >>= 1) {
        if (threadIdx.x < (unsigned)s) {
            sA[threadIdx.x] += sA[threadIdx.x+s];
            sB[threadIdx.x] += sB[threadIdx.x+s];
        }
        __syncthreads();
    }
    if (threadIdx.x == 0) { part[blockIdx.x] = make_double2(sA[0], sB[0]); }
}

// ---------------------------------------------------------------------------
// kD2: final reduce of 256 partials + v = max over b of (enc_last - enc_first)
// ---------------------------------------------------------------------------
__global__ __launch_bounds__(256) void kD2(const double2* __restrict__ part,
                                           const int* __restrict__ enci,
                                           float* __restrict__ out)
{
    __shared__ double sA[256], sB[256];
    const double2 pv = part[threadIdx.x];
    sA[threadIdx.x] = pv.x; sB[threadIdx.x] = pv.y;
    __syncthreads();
    for (int s = 128; s >= 1; s >>= 1) {
        if (threadIdx.x < (unsigned)s) {
            sA[threadIdx.x] += sA[threadIdx.x+s];
            sB[threadIdx.x] += sB[threadIdx.x+s];
        }
        __syncthreads();
    }
    if (threadIdx.x < 64) {
        int v = enci[(size_t)threadIdx.x*T_ + T_-1] - enci[(size_t)threadIdx.x*T_];
        #pragma unroll
        for (int m = 32; m >= 1; m >>= 1) {
            const int v2 = __shfl_xor(v, m);
            v = (v2 > v) ? v2 : v;
        }
        if (threadIdx.x == 0) {
            out[O_V]   = (float)v;
            out[O_EM]  = (float)(sA[0] / (double)P_);
            out[O_LED] = (float)(sB[0] / (double)(B_*(T_-1)));
        }
    }
}

// ---------------------------------------------------------------------------
extern "C" void kernel_launch(void* const* d_in, const int* in_sizes, int n_in,
                              void* d_out, int out_size, void* d_ws, size_t ws_size,
                              hipStream_t stream)
{
    const float* ks  = (const float*)d_in[0];
    const float* emb = (const float*)d_in[1];
    const unsigned char* mask = (const unsigned char*)d_in[2];

    float* out = (float*)d_out;
    char* w = (char*)d_ws;
    unsigned long long* bits = (unsigned long long*)(w);                      // 4 MB
    float* sfirst = (float*)(w + (size_t) 4*1024*1024);                       // 2 MB
    float* slast  = (float*)(w + (size_t) 6*1024*1024);                       // 2 MB
    float* minv   = (float*)(w + (size_t) 8*1024*1024);                       // 2 MB
    int*   mini   = (int*)  (w + (size_t)10*1024*1024);                       // 2 MB
    int*   enci   = (int*)  (w + (size_t)12*1024*1024);                       // 256 KB
    float* energy = (float*)(w + (size_t)12*1024*1024 + 256*1024);            // 256 KB
    float* sq     = (float*)(w + (size_t)12*1024*1024 + 512*1024);            // 4 KB
    double2* part = (double2*)(w + (size_t)12*1024*1024 + 516*1024);          // 4 KB

    kE <<<129,   256, 0, stream>>>(emb, sq);
    kA <<<2048,  256, 0, stream>>>(ks, emb, sq, bits, sfirst, slast, minv, mini);
    kB <<<B_,    64,  0, stream>>>(ks, emb, mask, bits, sfirst, slast, minv, mini, enci, out);
    kC <<<P_/4,  256, 0, stream>>>(ks, emb, enci, minv, mini, out, energy);
    kD1<<<256,   256, 0, stream>>>(energy, enci, part);
    kD2<<<1,     256, 0, stream>>>(part, enci, out);
}

// Round 3
// 446.265 us; speedup vs baseline: 2.0410x; 1.1350x over previous
//
#include <hip/hip_runtime.h>
#include <cfloat>
#include <cstdint>

#define B_  64
#define T_  1024
#define D_  128
#define NE  512            // clip limit; emb has NE+1 = 513 rows
#define P_  (B_*T_)        // 65536 positions

// d_out flat offsets (float32), in reference return order
#define O_KH   0
#define O_ENC  (P_*D_)             // 8388608
#define O_V    (O_ENC + P_)        // 8454144
#define O_LH   (O_V + 1)           // 8454145
#define O_LN   (O_LH + P_)         // 8519681
#define O_EM   (O_LN + P_)         // 8585217
#define O_LED  (O_EM + 1)          // 8585218

typedef __attribute__((ext_vector_type(8))) short bf16x8;
typedef __attribute__((ext_vector_type(4))) float floatx4;

// ---------------------------------------------------------------------------
// kE: sq[n] = ||emb_n||^2 for n = 0..512 (wave per row)
// ---------------------------------------------------------------------------
__global__ __launch_bounds__(256) void kE(const float* __restrict__ emb,
                                          float* __restrict__ sq)
{
    const int w = threadIdx.x >> 6, lane = threadIdx.x & 63;
    const int r = blockIdx.x * 4 + w;
    if (r > 512) return;
    const float2 e = ((const float2*)(emb + (size_t)r * D_))[lane];
    float s = e.x*e.x + e.y*e.y;
    #pragma unroll
    for (int m = 32; m >= 1; m >>= 1) s += __shfl_xor(s, m);
    if (lane == 0) sq[r] = s;
}

// ---------------------------------------------------------------------------
// kA: MFMA bf16 hi/lo 3-pass GEMM computing S[p][n] = sq[n] - 2*ks.emb for a
// 128p x 128n tile (K=128 in two 64-halves), then epilogue emits per-(p,
// 64-n-chunk) stay-bit ballot word, chunk argmin, boundary S values.
// LDS frag layout [kstep][quad][row][8 bf16]: every staging write and frag
// read is a lane-contiguous 16B-aligned ds_*_b128 (conflict-free).
// S noise from dropping kl*el: <= ~4e-7 abs; only decisions consume S.
// ---------------------------------------------------------------------------
__global__ __launch_bounds__(256, 2) void kA(const float* __restrict__ ks,
                                             const float* __restrict__ emb,
                                             const float* __restrict__ sq,
                                             unsigned long long* __restrict__ bits,
                                             float* __restrict__ sfirst,
                                             float* __restrict__ slast,
                                             float* __restrict__ minv,
                                             int* __restrict__ mini)
{
    __shared__ float sh[17152];            // 68608 B -> 2 blocks/CU
    char* Ah = (char*)sh;                  // 16 KB each
    char* Al = Ah + 16384;
    char* Bh = Ah + 32768;
    char* Bl = Ah + 49152;

    const int tid = threadIdx.x;
    const int bp  = blockIdx.x >> 2;
    const int bn  = blockIdx.x & 3;
    const int p0  = bp * 128;
    const int n0  = bn * 128;

    const int row = tid >> 1;              // staging row 0..127
    const int c32 = (tid & 1) * 32;        // staging k-offset within half

    const float* gA = ks  + (size_t)(p0 + row) * D_ + c32;
    const float* gB = emb + (size_t)(n0 + row) * D_ + c32;

    // hi = truncate(x) (low 16 mantissa bits dropped), lo = truncate(x - hi)
    auto cvt_store = [&](const float4* r8, char* hB, char* lB) {
        #pragma unroll
        for (int g = 0; g < 4; g++) {
            float v[8];
            v[0]=r8[2*g].x;   v[1]=r8[2*g].y;   v[2]=r8[2*g].z;   v[3]=r8[2*g].w;
            v[4]=r8[2*g+1].x; v[5]=r8[2*g+1].y; v[6]=r8[2*g+1].z; v[7]=r8[2*g+1].w;
            unsigned hw[4], lw[4];
            #pragma unroll
            for (int e = 0; e < 4; e++) {
                const unsigned ua = __float_as_uint(v[2*e]);
                const unsigned ub = __float_as_uint(v[2*e+1]);
                const float fa = __uint_as_float(ua & 0xffff0000u);
                const float fb = __uint_as_float(ub & 0xffff0000u);
                const unsigned da = __float_as_uint(v[2*e]   - fa);
                const unsigned db = __float_as_uint(v[2*e+1] - fb);
                hw[e] = (ub & 0xffff0000u) | (ua >> 16);
                lw[e] = (db & 0xffff0000u) | (da >> 16);
            }
            const int klocal0 = c32 + g*8;
            const int fi = ((klocal0 >> 5)*4 + ((klocal0 >> 3) & 3))*128 + row;
            *(uint4*)(hB + fi*16) = make_uint4(hw[0],hw[1],hw[2],hw[3]);
            *(uint4*)(lB + fi*16) = make_uint4(lw[0],lw[1],lw[2],lw[3]);
        }
    };

    floatx4 acc[4][4];
    #pragma unroll
    for (int i = 0; i < 4; i++)
        #pragma unroll
        for (int j = 0; j < 4; j++)
            #pragma unroll
            for (int r = 0; r < 4; r++) acc[i][j][r] = 0.f;

    const int wv   = tid >> 6;
    const int lane = tid & 63;
    const int wm = (wv & 1) * 64;          // wave tile 64x64
    const int wn = (wv >> 1) * 64;
    const int mq = lane >> 4;              // quad (k-group selector)
    const int mr = lane & 15;              // row within 16-subtile

    auto kloop = [&]() {
        #pragma unroll
        for (int kstep = 0; kstep < 2; kstep++) {
            const int fb = (kstep*4 + mq)*128;
            bf16x8 ah[4], al[4], bh[4], bl[4];
            #pragma unroll
            for (int s = 0; s < 4; s++) {
                ah[s] = *(const bf16x8*)(Ah + (fb + wm + s*16 + mr)*16);
                al[s] = *(const bf16x8*)(Al + (fb + wm + s*16 + mr)*16);
                bh[s] = *(const bf16x8*)(Bh + (fb + wn + s*16 + mr)*16);
                bl[s] = *(const bf16x8*)(Bl + (fb + wn + s*16 + mr)*16);
            }
            #pragma unroll
            for (int i = 0; i < 4; i++)
                #pragma unroll
                for (int j = 0; j < 4; j++)
                    acc[i][j] = __builtin_amdgcn_mfma_f32_16x16x32_bf16(ah[i], bh[j], acc[i][j], 0, 0, 0);
            #pragma unroll
            for (int i = 0; i < 4; i++)
                #pragma unroll
                for (int j = 0; j < 4; j++)
                    acc[i][j] = __builtin_amdgcn_mfma_f32_16x16x32_bf16(ah[i], bl[j], acc[i][j], 0, 0, 0);
            #pragma unroll
            for (int i = 0; i < 4; i++)
                #pragma unroll
                for (int j = 0; j < 4; j++)
                    acc[i][j] = __builtin_amdgcn_mfma_f32_16x16x32_bf16(al[i], bh[j], acc[i][j], 0, 0, 0);
        }
    };

    float4 ra[8], rb[8], ra2[8], rb2[8];
    // half 0: load + convert + stage
    #pragma unroll
    for (int i = 0; i < 8; i++) ra[i] = ((const float4*)gA)[i];
    #pragma unroll
    for (int i = 0; i < 8; i++) rb[i] = ((const float4*)gB)[i];
    cvt_store(ra, Ah, Al);
    cvt_store(rb, Bh, Bl);
    __syncthreads();
    // prefetch half 1 while computing half 0
    #pragma unroll
    for (int i = 0; i < 8; i++) ra2[i] = ((const float4*)(gA + 64))[i];
    #pragma unroll
    for (int i = 0; i < 8; i++) rb2[i] = ((const float4*)(gB + 64))[i];
    kloop();                               // half 0
    __syncthreads();
    cvt_store(ra2, Ah, Al);
    cvt_store(rb2, Bh, Bl);
    __syncthreads();
    kloop();                               // half 1

    // ---- epilogue: S tile to LDS, then ballot/argmin per (p, 64-chunk) ----
    float qv[4];
    #pragma unroll
    for (int j = 0; j < 4; j++) qv[j] = sq[n0 + wn + j*16 + mr];
    __syncthreads();                       // all frag reads done
    float* Sld = sh;                       // [128][132] = 16896 floats
    #pragma unroll
    for (int i = 0; i < 4; i++)
        #pragma unroll
        for (int j = 0; j < 4; j++) {
            const int nl = wn + j*16 + mr;
            #pragma unroll
            for (int r = 0; r < 4; r++) {
                const int pl = wm + i*16 + mq*4 + r;   // C/D: row = quad*4+reg
                Sld[pl*132 + nl] = fmaf(-2.f, acc[i][j][r], qv[j]);
            }
        }
    __syncthreads();

    for (int idx = wv; idx < 256; idx += 4) {  // 128 p x 2 chunks
        const int p = idx >> 1;
        const int c = idx & 1;
        const float S   = Sld[p*132 + c*64 + lane];
        const float Snx = __shfl_down(S, 1);
        const unsigned long long bw = __ballot(S <= Snx); // bit63 patched in kB
        float mv = S; int mi = n0 + c*64 + lane;
        #pragma unroll
        for (int m = 32; m >= 1; m >>= 1) {
            const float v2 = __shfl_xor(mv, m);
            const int   i2 = __shfl_xor(mi, m);
            if (v2 < mv || (v2 == mv && i2 < mi)) { mv = v2; mi = i2; }
        }
        const size_t pg = (size_t)(p0 + p);
        const int    cg = bn*2 + c;
        if (lane == 0) {
            bits  [pg*8 + cg] = bw;
            sfirst[pg*8 + cg] = S;
            minv  [pg*8 + cg] = mv;
            mini  [pg*8 + cg] = mi;
        }
        if (lane == 63) slast[pg*8 + cg] = S;
    }
}

// ---------------------------------------------------------------------------
// kB: one wave per b. Patch chunk-boundary stay bits, ind0 from global
// argmin at t=0, speculative 64-wide wave scan over t.
// ---------------------------------------------------------------------------
__global__ __launch_bounds__(64) void kB(const float* __restrict__ ks,
                                         const float* __restrict__ emb,
                                         const unsigned char* __restrict__ mask,
                                         const unsigned long long* __restrict__ bits,
                                         const float* __restrict__ sfirst,
                                         const float* __restrict__ slast,
                                         const float* __restrict__ minv,
                                         const int* __restrict__ mini,
                                         int* __restrict__ enci,
                                         float* __restrict__ out)
{
    __shared__ unsigned long long lb[T_ * 8];   // 64 KB
    const int b    = blockIdx.x;
    const int lane = threadIdx.x;

    for (int i = lane; i < T_*8; i += 64) {
        const int t = i >> 3, c = i & 7;
        const size_t p = (size_t)b*T_ + t;
        unsigned long long w = bits[p*8 + c] & 0x7fffffffffffffffULL;
        bool stay63 = (c < 7) ? (slast[p*8 + c] <= sfirst[p*8 + c + 1]) : true;
        if (stay63) w |= 0x8000000000000000ULL;
        lb[i] = w;
    }
    __syncthreads();

    const size_t p0 = (size_t)b * T_;
    {
        const float2 e = ((const float2*)(emb + (size_t)512*D_))[lane];
        const float2 k = ((const float2*)(ks  + p0*D_))[lane];
        float s5 = e.x*(e.x - 2.f*k.x) + e.y*(e.y - 2.f*k.y);
        #pragma unroll
        for (int m = 32; m >= 1; m >>= 1) s5 += __shfl_xor(s5, m);

        float mv; int mi;
        if (lane < 8)       { mv = minv[p0*8 + lane]; mi = mini[p0*8 + lane]; }
        else if (lane == 8) { mv = s5; mi = 512; }
        else                { mv = FLT_MAX; mi = 0x7fffffff; }
        #pragma unroll
        for (int m = 32; m >= 1; m >>= 1) {
            float v2 = __shfl_xor(mv, m);
            int   i2 = __shfl_xor(mi, m);
            if (v2 < mv || (v2 == mv && i2 < mi)) { mv = v2; mi = i2; }
        }
        int cur = (mi < NE) ? mi : NE - 1;
        if (mask[b]) cur = 0;
        if (lane == 0) { enci[p0] = cur; out[O_ENC + p0] = (float)cur; }

        for (int t0 = 1; t0 < T_; t0 += 64) {
            const int w0 = cur >> 6;
            const int w1 = (w0 < 7) ? w0 + 1 : 7;
            const int t  = t0 + lane;
            unsigned long long u0 = 0, u1 = 0;
            if (t < T_) { u0 = lb[t*8 + w0]; u1 = lb[t*8 + w1]; }
            const int base = w0 << 6;
            int myenc = cur;
            const int nst = (T_ - t0 < 64) ? (T_ - t0) : 64;
            for (int j = 0; j < nst; j++) {
                const unsigned long long a0 = __shfl(u0, j);
                const unsigned long long a1 = __shfl(u1, j);
                const int off = cur - base;
                const int bit = (off < 64) ? (int)((a0 >> off) & 1ULL)
                                           : (int)((a1 >> (off - 64)) & 1ULL);
                cur += 1 - bit;
                if (lane == j) myenc = cur;
            }
            if (t < T_) { enci[p0 + t] = myenc; out[O_ENC + p0 + t] = (float)myenc; }
        }
    }
}

// ---------------------------------------------------------------------------
// kC: one wave per position. Recompute S at {enc, enc+1, 512, argmin} via
// fp32 wave dot-products; emit key_hard, loss_here, loss_next, energy.
// ---------------------------------------------------------------------------
__global__ __launch_bounds__(256) void kC(const float* __restrict__ ks,
                                          const float* __restrict__ emb,
                                          const int* __restrict__ enci,
                                          const float* __restrict__ minv,
                                          const int* __restrict__ mini,
                                          float* __restrict__ out,
                                          float* __restrict__ energy)
{
    const int lane = threadIdx.x & 63;
    const size_t p = (size_t)blockIdx.x * 4 + (threadIdx.x >> 6);

    const float2 k  = ((const float2*)(ks + p*D_))[lane];
    const int eh = enci[p];
    const int en = (eh + 1 < NE) ? eh + 1 : NE - 1;
    const float2 Eh = ((const float2*)(emb + (size_t)eh*D_))[lane];
    const float2 En = ((const float2*)(emb + (size_t)en*D_))[lane];
    const float2 E5 = ((const float2*)(emb + (size_t)512*D_))[lane];

    float ph  = Eh.x*(Eh.x - 2.f*k.x) + Eh.y*(Eh.y - 2.f*k.y);
    float pn  = En.x*(En.x - 2.f*k.x) + En.y*(En.y - 2.f*k.y);
    float p5  = E5.x*(E5.x - 2.f*k.x) + E5.y*(E5.y - 2.f*k.y);
    float sqk = k.x*k.x + k.y*k.y;
    #pragma unroll
    for (int m = 32; m >= 1; m >>= 1) {
        ph  += __shfl_xor(ph, m);
        pn  += __shfl_xor(pn, m);
        p5  += __shfl_xor(p5, m);
        sqk += __shfl_xor(sqk, m);
    }

    float mv; int mi;
    if (lane < 8)       { mv = minv[p*8 + lane]; mi = mini[p*8 + lane]; }
    else if (lane == 8) { mv = p5; mi = 512; }
    else                { mv = FLT_MAX; mi = 0x7fffffff; }
    #pragma unroll
    for (int m = 32; m >= 1; m >>= 1) {
        float v2 = __shfl_xor(mv, m);
        int   i2 = __shfl_xor(mi, m);
        if (v2 < mv || (v2 == mv && i2 < mi)) { mv = v2; mi = i2; }
    }

    const float2 Em = ((const float2*)(emb + (size_t)mi*D_))[lane];
    float pm = Em.x*(Em.x - 2.f*k.x) + Em.y*(Em.y - 2.f*k.y);
    #pragma unroll
    for (int m = 32; m >= 1; m >>= 1) pm += __shfl_xor(pm, m);

    const float lh = 1.2f * (sqk + ph);
    const float ln = 1.2f * (sqk + pn);
    const float lm = 1.2f * (sqk + pm);
    const float lossh = lh - ln - ((pm < ph) ? lm : 0.f);
    const float lossn = ln - lh - ((pm < pn) ? lm : 0.f);

    float2 kh;
    kh.x = k.x + (Eh.x - k.x);
    kh.y = k.y + (Eh.y - k.y);
    ((float2*)(out + p*D_))[lane] = kh;

    if (lane == 0) {
        out[O_LH + p] = lossh;
        out[O_LN + p] = lossn;
        energy[p] = 1.2f * (pn - ph);
    }
}

// ---------------------------------------------------------------------------
// kD1: per-256-position partial sums (energy, energy-descent terms)
// ---------------------------------------------------------------------------
__global__ __launch_bounds__(256) void kD1(const float* __restrict__ energy,
                                           const int* __restrict__ enci,
                                           double2* __restrict__ part)
{
    __shared__ double sA[256], sB[256];
    const int p = blockIdx.x * 256 + threadIdx.x;
    const float e = energy[p];
    double se = (double)e;
    double sl = 0.0;
    if ((p & (T_-1)) < T_-1) {
        const float ec = (enci[p+1] == enci[p]) ? (energy[p+1] - e) : 0.f;
        sl = (double)fmaxf(ec + (float)(1e-6/512.0), 0.f);
    }
    sA[threadIdx.x] = se; sB[threadIdx.x] = sl;
    __syncthreads();
    for (int s = 128; s >= 1; s >>= 1) {
        if (threadIdx.x < (unsigned)s) {
            sA[threadIdx.x] += sA[threadIdx.x+s];
            sB[threadIdx.x] += sB[threadIdx.x+s];
        }
        __syncthreads();
    }
    if (threadIdx.x == 0) { part[blockIdx.x] = make_double2(sA[0], sB[0]); }
}

// ---------------------------------------------------------------------------
// kD2: final reduce of 256 partials + v = max over b of (enc_last - enc_first)
// ---------------------------------------------------------------------------
__global__ __launch_bounds__(256) void kD2(const double2* __restrict__ part,
                                           const int* __restrict__ enci,
                                           float* __restrict__ out)
{
    __shared__ double sA[256], sB[256];
    const double2 pv = part[threadIdx.x];
    sA[threadIdx.x] = pv.x; sB[threadIdx.x] = pv.y;
    __syncthreads();
    for (int s = 128; s >= 1; s >>= 1) {
        if (threadIdx.x < (unsigned)s) {
            sA[threadIdx.x] += sA[threadIdx.x+s];
            sB[threadIdx.x] += sB[threadIdx.x+s];
        }
        __syncthreads();
    }
    if (threadIdx.x < 64) {
        int v = enci[(size_t)threadIdx.x*T_ + T_-1] - enci[(size_t)threadIdx.x*T_];
        #pragma unroll
        for (int m = 32; m >= 1; m >>= 1) {
            const int v2 = __shfl_xor(v, m);
            v = (v2 > v) ? v2 : v;
        }
        if (threadIdx.x == 0) {
            out[O_V]   = (float)v;
            out[O_EM]  = (float)(sA[0] / (double)P_);
            out[O_LED] = (float)(sB[0] / (double)(B_*(T_-1)));
        }
    }
}

// ---------------------------------------------------------------------------
extern "C" void kernel_launch(void* const* d_in, const int* in_sizes, int n_in,
                              void* d_out, int out_size, void* d_ws, size_t ws_size,
                              hipStream_t stream)
{
    const float* ks  = (const float*)d_in[0];
    const float* emb = (const float*)d_in[1];
    const unsigned char* mask = (const unsigned char*)d_in[2];

    float* out = (float*)d_out;
    char* w = (char*)d_ws;
    unsigned long long* bits = (unsigned long long*)(w);                      // 4 MB
    float* sfirst = (float*)(w + (size_t) 4*1024*1024);                       // 2 MB
    float* slast  = (float*)(w + (size_t) 6*1024*1024);                       // 2 MB
    float* minv   = (float*)(w + (size_t) 8*1024*1024);                       // 2 MB
    int*   mini   = (int*)  (w + (size_t)10*1024*1024);                       // 2 MB
    int*   enci   = (int*)  (w + (size_t)12*1024*1024);                       // 256 KB
    float* energy = (float*)(w + (size_t)12*1024*1024 + 256*1024);            // 256 KB
    float* sq     = (float*)(w + (size_t)12*1024*1024 + 512*1024);            // 4 KB
    double2* part = (double2*)(w + (size_t)12*1024*1024 + 516*1024);          // 4 KB

    kE <<<129,   256, 0, stream>>>(emb, sq);
    kA <<<2048,  256, 0, stream>>>(ks, emb, sq, bits, sfirst, slast, minv, mini);
    kB <<<B_,    64,  0, stream>>>(ks, emb, mask, bits, sfirst, slast, minv, mini, enci, out);
    kC <<<P_/4,  256, 0, stream>>>(ks, emb, enci, minv, mini, out, energy);
    kD1<<<256,   256, 0, stream>>>(energy, enci, part);
    kD2<<<1,     256, 0, stream>>>(part, enci, out);
}

// Round 4
// 283.215 us; speedup vs baseline: 3.2160x; 1.5757x over previous
//
#include <hip/hip_runtime.h>
#include <cfloat>
#include <cstdint>

#define B_  64
#define T_  1024
#define D_  128
#define NE  512            // clip limit; emb has NE+1 = 513 rows
#define P_  (B_*T_)        // 65536 positions

// d_out flat offsets (float32), in reference return order
#define O_KH   0
#define O_ENC  (P_*D_)             // 8388608
#define O_V    (O_ENC + P_)        // 8454144
#define O_LH   (O_V + 1)           // 8454145
#define O_LN   (O_LH + P_)         // 8519681
#define O_EM   (O_LN + P_)         // 8585217
#define O_LED  (O_EM + 1)          // 8585218

typedef __attribute__((ext_vector_type(8))) short bf16x8;
typedef __attribute__((ext_vector_type(4))) float floatx4;

// hi = truncate-to-bf16(x), lo = truncate-to-bf16(x - hi); pack 8 floats ->
// two uint4 (8 bf16 each, k-ascending little-endian)
__device__ __forceinline__ void pack8(const float4& a, const float4& b,
                                      uint4& h, uint4& l)
{
    float v[8] = {a.x,a.y,a.z,a.w,b.x,b.y,b.z,b.w};
    unsigned hw[4], lw[4];
    #pragma unroll
    for (int e = 0; e < 4; e++) {
        const unsigned ua = __float_as_uint(v[2*e]);
        const unsigned ub = __float_as_uint(v[2*e+1]);
        const float fa = __uint_as_float(ua & 0xffff0000u);
        const float fb = __uint_as_float(ub & 0xffff0000u);
        const unsigned da = __float_as_uint(v[2*e]   - fa);
        const unsigned db = __float_as_uint(v[2*e+1] - fb);
        hw[e] = (ub & 0xffff0000u) | (ua >> 16);
        lw[e] = (db & 0xffff0000u) | (da >> 16);
    }
    h = make_uint4(hw[0],hw[1],hw[2],hw[3]);
    l = make_uint4(lw[0],lw[1],lw[2],lw[3]);
}

__device__ __forceinline__ unsigned long long shflx64(unsigned long long v, int d)
{
    const int lo = __shfl_xor((int)(unsigned)(v & 0xffffffffULL), d);
    const int hi = __shfl_xor((int)(unsigned)(v >> 32), d);
    return ((unsigned long long)(unsigned)hi << 32) | (unsigned)lo;
}

// ---------------------------------------------------------------------------
// kE: sq[n] = ||emb_n||^2 for n = 0..512 (wave per row)
// ---------------------------------------------------------------------------
__global__ __launch_bounds__(256) void kE(const float* __restrict__ emb,
                                          float* __restrict__ sq)
{
    const int w = threadIdx.x >> 6, lane = threadIdx.x & 63;
    const int r = blockIdx.x * 4 + w;
    if (r > 512) return;
    const float2 e = ((const float2*)(emb + (size_t)r * D_))[lane];
    float s = e.x*e.x + e.y*e.y;
    #pragma unroll
    for (int m = 32; m >= 1; m >>= 1) s += __shfl_xor(s, m);
    if (lane == 0) sq[r] = s;
}

// ---------------------------------------------------------------------------
// kF: pre-convert emb (rows 0..511) to bf16 hi/lo in MFMA A-frag layout:
// frag slot f = ((n>>4)*4 + kstep)*4 + quad holds 16 lanes x 8 bf16
// (lane = n&15, halves = k ascending). 128 KB per array, L2-resident.
// ---------------------------------------------------------------------------
__global__ __launch_bounds__(256) void kF(const float* __restrict__ emb,
                                          unsigned short* __restrict__ ehi,
                                          unsigned short* __restrict__ elo)
{
    const int t = blockIdx.x * 256 + threadIdx.x;     // 0..2047
    const int n = t >> 2, kst = t & 3;
    const float4* src = (const float4*)(emb + (size_t)n * D_ + kst * 32);
    #pragma unroll
    for (int q = 0; q < 4; q++) {
        uint4 h, l;
        pack8(src[2*q], src[2*q+1], h, l);
        const size_t f = ((size_t)(n >> 4) * 4 + kst) * 4 + q;
        *(uint4*)(ehi + f*128 + (size_t)(n & 15)*8) = h;
        *(uint4*)(elo + f*128 + (size_t)(n & 15)*8) = l;
    }
}

// ---------------------------------------------------------------------------
// kA: transposed MFMA GEMM. Block = 64 p-cols x all 512 n. 4 waves; wave w
// handles n-chunks {w, w+4} (64 n each). A (emb) frags from global kF arrays;
// B (ks) staged once into LDS bf16 hi/lo in frag layout. hi/lo 3-pass MFMA.
// Epilogue: C/D layout gives each lane 4 consecutive n per i-tile -> stay
// bits are register-local compares; 2 cross-quad OR-shuffles assemble the
// 64-bit chunk word; argmin is 16 local compares + 2 shuffle levels.
// Same output interface as before (bits/sfirst/slast/minv/mini).
// ---------------------------------------------------------------------------
__global__ __launch_bounds__(256) void kA(const float* __restrict__ ks,
                                          const float* __restrict__ sq,
                                          const unsigned short* __restrict__ ehi,
                                          const unsigned short* __restrict__ elo,
                                          unsigned long long* __restrict__ bits,
                                          float* __restrict__ sfirst,
                                          float* __restrict__ slast,
                                          float* __restrict__ minv,
                                          int* __restrict__ mini)
{
    __shared__ unsigned short Bhi[16*64*8];   // 16 KB: [kq][p_local][8]
    __shared__ unsigned short Blo[16*64*8];   // 16 KB

    const int tid  = threadIdx.x;
    const int lane = tid & 63;
    const int wv   = tid >> 6;
    const int m    = lane & 15;               // p within 16-tile / A-lane row
    const int q    = lane >> 4;               // quad
    const int p0   = blockIdx.x * 64;

    // ---- stage ks tile (64 p x 128 k) as bf16 hi/lo frags ----
    {
        const int row = tid >> 2;             // p_local 0..63
        const int kh  = tid & 3;              // k-quarter (32 k)
        const float4* src = (const float4*)(ks + (size_t)(p0 + row) * D_ + kh * 32);
        #pragma unroll
        for (int g = 0; g < 4; g++) {
            uint4 h, l;
            pack8(src[2*g], src[2*g+1], h, l);
            const int kq = kh*4 + g;
            *(uint4*)&Bhi[(kq*64 + row)*8] = h;
            *(uint4*)&Blo[(kq*64 + row)*8] = l;
        }
    }
    __syncthreads();

    for (int cc = 0; cc < 2; cc++) {
        const int ch = wv + cc*4;             // chunk 0..7
        const int nb = ch * 64;               // chunk base n

        floatx4 acc[4][4];
        #pragma unroll
        for (int i = 0; i < 4; i++)
            #pragma unroll
            for (int j = 0; j < 4; j++)
                #pragma unroll
                for (int r = 0; r < 4; r++) acc[i][j][r] = 0.f;

        #pragma unroll 1
        for (int kst = 0; kst < 4; kst++) {
            bf16x8 ah[4], al[4], bh[4], bl[4];
            #pragma unroll
            for (int i = 0; i < 4; i++) {
                const size_t f = ((size_t)(ch*4 + i) * 4 + kst) * 4 + q;
                ah[i] = *(const bf16x8*)(ehi + f*128 + (size_t)m*8);
                al[i] = *(const bf16x8*)(elo + f*128 + (size_t)m*8);
            }
            const int kq = kst*4 + q;
            #pragma unroll
            for (int j = 0; j < 4; j++) {
                bh[j] = *(const bf16x8*)&Bhi[(kq*64 + j*16 + m)*8];
                bl[j] = *(const bf16x8*)&Blo[(kq*64 + j*16 + m)*8];
            }
            #pragma unroll
            for (int i = 0; i < 4; i++)
                #pragma unroll
                for (int j = 0; j < 4; j++)
                    acc[i][j] = __builtin_amdgcn_mfma_f32_16x16x32_bf16(ah[i], bh[j], acc[i][j], 0, 0, 0);
            #pragma unroll
            for (int i = 0; i < 4; i++)
                #pragma unroll
                for (int j = 0; j < 4; j++)
                    acc[i][j] = __builtin_amdgcn_mfma_f32_16x16x32_bf16(ah[i], bl[j], acc[i][j], 0, 0, 0);
            #pragma unroll
            for (int i = 0; i < 4; i++)
                #pragma unroll
                for (int j = 0; j < 4; j++)
                    acc[i][j] = __builtin_amdgcn_mfma_f32_16x16x32_bf16(al[i], bh[j], acc[i][j], 0, 0, 0);
        }

        // ---- epilogue ----
        float sa[4][4];
        #pragma unroll
        for (int i = 0; i < 4; i++) {
            const float4 s4 = *(const float4*)(sq + nb + i*16 + q*4);
            sa[i][0]=s4.x; sa[i][1]=s4.y; sa[i][2]=s4.z; sa[i][3]=s4.w;
        }
        #pragma unroll
        for (int j = 0; j < 4; j++) {
            float S[4][4];
            #pragma unroll
            for (int i = 0; i < 4; i++)
                #pragma unroll
                for (int r = 0; r < 4; r++)
                    S[i][r] = fmaf(-2.f, acc[i][j][r], sa[i][r]);

            // neighbor S at quad/tile boundaries
            float nq[4], ni[4];
            #pragma unroll
            for (int i = 0; i < 4; i++) nq[i] = __shfl_down(S[i][0], 16);
            #pragma unroll
            for (int i = 0; i < 3; i++) ni[i] = __shfl(S[i+1][0], m);
            ni[3] = 0.f;                       // bit63 garbage, patched in kB

            unsigned long long w = 0;
            #pragma unroll
            for (int i = 0; i < 4; i++) {
                #pragma unroll
                for (int r = 0; r < 3; r++)
                    w |= (unsigned long long)(S[i][r] <= S[i][r+1]) << (16*i + 4*q + r);
                const float nxt = (q < 3) ? nq[i] : ni[i];
                w |= (unsigned long long)(S[i][3] <= nxt) << (16*i + 4*q + 3);
            }
            w |= shflx64(w, 16);
            w |= shflx64(w, 32);

            // chunk argmin (first-index tie-break; ascending local scan)
            float mv = S[0][0]; int mi_ = nb + q*4;
            #pragma unroll
            for (int i = 0; i < 4; i++)
                #pragma unroll
                for (int r = 0; r < 4; r++) {
                    if (i == 0 && r == 0) continue;
                    const int nid = nb + 16*i + 4*q + r;
                    if (S[i][r] < mv) { mv = S[i][r]; mi_ = nid; }
                }
            #pragma unroll
            for (int d = 16; d <= 32; d <<= 1) {
                const float v2 = __shfl_xor(mv, d);
                const int   i2 = __shfl_xor(mi_, d);
                if (v2 < mv || (v2 == mv && i2 < mi_)) { mv = v2; mi_ = i2; }
            }

            const size_t pg = (size_t)(p0 + j*16 + m);
            if (q == 0) {
                bits  [pg*8 + ch] = w;
                sfirst[pg*8 + ch] = S[0][0];
                minv  [pg*8 + ch] = mv;
                mini  [pg*8 + ch] = mi_;
            }
            if (q == 3) slast[pg*8 + ch] = S[3][3];
        }
    }
}

// ---------------------------------------------------------------------------
// kB: one wave per b. Patch chunk-boundary stay bits, ind0 from global
// argmin at t=0, speculative 64-wide wave scan over t.
// ---------------------------------------------------------------------------
__global__ __launch_bounds__(64) void kB(const float* __restrict__ ks,
                                         const float* __restrict__ emb,
                                         const unsigned char* __restrict__ mask,
                                         const unsigned long long* __restrict__ bits,
                                         const float* __restrict__ sfirst,
                                         const float* __restrict__ slast,
                                         const float* __restrict__ minv,
                                         const int* __restrict__ mini,
                                         int* __restrict__ enci,
                                         float* __restrict__ out)
{
    __shared__ unsigned long long lb[T_ * 8];   // 64 KB
    const int b    = blockIdx.x;
    const int lane = threadIdx.x;

    for (int i = lane; i < T_*8; i += 64) {
        const int t = i >> 3, c = i & 7;
        const size_t p = (size_t)b*T_ + t;
        unsigned long long w = bits[p*8 + c] & 0x7fffffffffffffffULL;
        bool stay63 = (c < 7) ? (slast[p*8 + c] <= sfirst[p*8 + c + 1]) : true;
        if (stay63) w |= 0x8000000000000000ULL;
        lb[i] = w;
    }
    __syncthreads();

    const size_t p0 = (size_t)b * T_;
    {
        const float2 e = ((const float2*)(emb + (size_t)512*D_))[lane];
        const float2 k = ((const float2*)(ks  + p0*D_))[lane];
        float s5 = e.x*(e.x - 2.f*k.x) + e.y*(e.y - 2.f*k.y);
        #pragma unroll
        for (int m = 32; m >= 1; m >>= 1) s5 += __shfl_xor(s5, m);

        float mv; int mi;
        if (lane < 8)       { mv = minv[p0*8 + lane]; mi = mini[p0*8 + lane]; }
        else if (lane == 8) { mv = s5; mi = 512; }
        else                { mv = FLT_MAX; mi = 0x7fffffff; }
        #pragma unroll
        for (int m = 32; m >= 1; m >>= 1) {
            float v2 = __shfl_xor(mv, m);
            int   i2 = __shfl_xor(mi, m);
            if (v2 < mv || (v2 == mv && i2 < mi)) { mv = v2; mi = i2; }
        }
        int cur = (mi < NE) ? mi : NE - 1;
        if (mask[b]) cur = 0;
        if (lane == 0) { enci[p0] = cur; out[O_ENC + p0] = (float)cur; }

        for (int t0 = 1; t0 < T_; t0 += 64) {
            const int w0 = cur >> 6;
            const int w1 = (w0 < 7) ? w0 + 1 : 7;
            const int t  = t0 + lane;
            unsigned long long u0 = 0, u1 = 0;
            if (t < T_) { u0 = lb[t*8 + w0]; u1 = lb[t*8 + w1]; }
            const int base = w0 << 6;
            int myenc = cur;
            const int nst = (T_ - t0 < 64) ? (T_ - t0) : 64;
            for (int j = 0; j < nst; j++) {
                const unsigned long long a0 = __shfl(u0, j);
                const unsigned long long a1 = __shfl(u1, j);
                const int off = cur - base;
                const int bit = (off < 64) ? (int)((a0 >> off) & 1ULL)
                                           : (int)((a1 >> (off - 64)) & 1ULL);
                cur += 1 - bit;
                if (lane == j) myenc = cur;
            }
            if (t < T_) { enci[p0 + t] = myenc; out[O_ENC + p0 + t] = (float)myenc; }
        }
    }
}

// ---------------------------------------------------------------------------
// kC: one wave per position. Recompute S at {enc, enc+1, 512, argmin} via
// fp32 wave dot-products; emit key_hard, loss_here, loss_next, energy.
// ---------------------------------------------------------------------------
__global__ __launch_bounds__(256) void kC(const float* __restrict__ ks,
                                          const float* __restrict__ emb,
                                          const int* __restrict__ enci,
                                          const float* __restrict__ minv,
                                          const int* __restrict__ mini,
                                          float* __restrict__ out,
                                          float* __restrict__ energy)
{
    const int lane = threadIdx.x & 63;
    const size_t p = (size_t)blockIdx.x * 4 + (threadIdx.x >> 6);

    const float2 k  = ((const float2*)(ks + p*D_))[lane];
    const int eh = enci[p];
    const int en = (eh + 1 < NE) ? eh + 1 : NE - 1;
    const float2 Eh = ((const float2*)(emb + (size_t)eh*D_))[lane];
    const float2 En = ((const float2*)(emb + (size_t)en*D_))[lane];
    const float2 E5 = ((const float2*)(emb + (size_t)512*D_))[lane];

    float ph  = Eh.x*(Eh.x - 2.f*k.x) + Eh.y*(Eh.y - 2.f*k.y);
    float pn  = En.x*(En.x - 2.f*k.x) + En.y*(En.y - 2.f*k.y);
    float p5  = E5.x*(E5.x - 2.f*k.x) + E5.y*(E5.y - 2.f*k.y);
    float sqk = k.x*k.x + k.y*k.y;
    #pragma unroll
    for (int m = 32; m >= 1; m >>= 1) {
        ph  += __shfl_xor(ph, m);
        pn  += __shfl_xor(pn, m);
        p5  += __shfl_xor(p5, m);
        sqk += __shfl_xor(sqk, m);
    }

    float mv; int mi;
    if (lane < 8)       { mv = minv[p*8 + lane]; mi = mini[p*8 + lane]; }
    else if (lane == 8) { mv = p5; mi = 512; }
    else                { mv = FLT_MAX; mi = 0x7fffffff; }
    #pragma unroll
    for (int m = 32; m >= 1; m >>= 1) {
        float v2 = __shfl_xor(mv, m);
        int   i2 = __shfl_xor(mi, m);
        if (v2 < mv || (v2 == mv && i2 < mi)) { mv = v2; mi = i2; }
    }

    const float2 Em = ((const float2*)(emb + (size_t)mi*D_))[lane];
    float pm = Em.x*(Em.x - 2.f*k.x) + Em.y*(Em.y - 2.f*k.y);
    #pragma unroll
    for (int m = 32; m >= 1; m >>= 1) pm += __shfl_xor(pm, m);

    const float lh = 1.2f * (sqk + ph);
    const float ln = 1.2f * (sqk + pn);
    const float lm = 1.2f * (sqk + pm);
    const float lossh = lh - ln - ((pm < ph) ? lm : 0.f);
    const float lossn = ln - lh - ((pm < pn) ? lm : 0.f);

    float2 kh;
    kh.x = k.x + (Eh.x - k.x);
    kh.y = k.y + (Eh.y - k.y);
    ((float2*)(out + p*D_))[lane] = kh;

    if (lane == 0) {
        out[O_LH + p] = lossh;
        out[O_LN + p] = lossn;
        energy[p] = 1.2f * (pn - ph);
    }
}

// ---------------------------------------------------------------------------
// kD1: per-256-position partial sums (energy, energy-descent terms)
// ---------------------------------------------------------------------------
__global__ __launch_bounds__(256) void kD1(const float* __restrict__ energy,
                                           const int* __restrict__ enci,
                                           double2* __restrict__ part)
{
    __shared__ double sA[256], sB[256];
    const int p = blockIdx.x * 256 + threadIdx.x;
    const float e = energy[p];
    double se = (double)e;
    double sl = 0.0;
    if ((p & (T_-1)) < T_-1) {
        const float ec = (enci[p+1] == enci[p]) ? (energy[p+1] - e) : 0.f;
        sl = (double)fmaxf(ec + (float)(1e-6/512.0), 0.f);
    }
    sA[threadIdx.x] = se; sB[threadIdx.x] = sl;
    __syncthreads();
    for (int s = 128; s >= 1; s >>= 1) {
        if (threadIdx.x < (unsigned)s) {
            sA[threadIdx.x] += sA[threadIdx.x+s];
            sB[threadIdx.x] += sB[threadIdx.x+s];
        }
        __syncthreads();
    }
    if (threadIdx.x == 0) { part[blockIdx.x] = make_double2(sA[0], sB[0]); }
}

// ---------------------------------------------------------------------------
// kD2: final reduce of 256 partials + v = max over b of (enc_last - enc_first)
// ---------------------------------------------------------------------------
__global__ __launch_bounds__(256) void kD2(const double2* __restrict__ part,
                                           const int* __restrict__ enci,
                                           float* __restrict__ out)
{
    __shared__ double sA[256], sB[256];
    const double2 pv = part[threadIdx.x];
    sA[threadIdx.x] = pv.x; sB[threadIdx.x] = pv.y;
    __syncthreads();
    for (int s = 128; s >= 1; s >>= 1) {
        if (threadIdx.x < (unsigned)s) {
            sA[threadIdx.x] += sA[threadIdx.x+s];
            sB[threadIdx.x] += sB[threadIdx.x+s];
        }
        __syncthreads();
    }
    if (threadIdx.x < 64) {
        int v = enci[(size_t)threadIdx.x*T_ + T_-1] - enci[(size_t)threadIdx.x*T_];
        #pragma unroll
        for (int m = 32; m >= 1; m >>= 1) {
            const int v2 = __shfl_xor(v, m);
            v = (v2 > v) ? v2 : v;
        }
        if (threadIdx.x == 0) {
            out[O_V]   = (float)v;
            out[O_EM]  = (float)(sA[0] / (double)P_);
            out[O_LED] = (float)(sB[0] / (double)(B_*(T_-1)));
        }
    }
}

// ---------------------------------------------------------------------------
extern "C" void kernel_launch(void* const* d_in, const int* in_sizes, int n_in,
                              void* d_out, int out_size, void* d_ws, size_t ws_size,
                              hipStream_t stream)
{
    const float* ks  = (const float*)d_in[0];
    const float* emb = (const float*)d_in[1];
    const unsigned char* mask = (const unsigned char*)d_in[2];

    float* out = (float*)d_out;
    char* w = (char*)d_ws;
    unsigned long long* bits = (unsigned long long*)(w);                      // 4 MB
    float* sfirst = (float*)(w + (size_t) 4*1024*1024);                       // 2 MB
    float* slast  = (float*)(w + (size_t) 6*1024*1024);                       // 2 MB
    float* minv   = (float*)(w + (size_t) 8*1024*1024);                       // 2 MB
    int*   mini   = (int*)  (w + (size_t)10*1024*1024);                       // 2 MB
    int*   enci   = (int*)  (w + (size_t)12*1024*1024);                       // 256 KB
    float* energy = (float*)(w + (size_t)12*1024*1024 + 256*1024);            // 256 KB
    float* sq     = (float*)(w + (size_t)12*1024*1024 + 512*1024);            // 4 KB
    double2* part = (double2*)(w + (size_t)12*1024*1024 + 516*1024);          // 4 KB
    unsigned short* ehi = (unsigned short*)(w + (size_t)12*1024*1024 + 640*1024); // 128 KB
    unsigned short* elo = (unsigned short*)(w + (size_t)12*1024*1024 + 768*1024); // 128 KB

    kE <<<129,  256, 0, stream>>>(emb, sq);
    kF <<<8,    256, 0, stream>>>(emb, ehi, elo);
    kA <<<1024, 256, 0, stream>>>(ks, sq, ehi, elo, bits, sfirst, slast, minv, mini);
    kB <<<B_,   64,  0, stream>>>(ks, emb, mask, bits, sfirst, slast, minv, mini, enci, out);
    kC <<<P_/4, 256, 0, stream>>>(ks, emb, enci, minv, mini, out, energy);
    kD1<<<256,  256, 0, stream>>>(energy, enci, part);
    kD2<<<1,    256, 0, stream>>>(part, enci, out);
}

// Round 5
// 214.487 us; speedup vs baseline: 4.2465x; 1.3204x over previous
//
#include <hip/hip_runtime.h>
#include <cfloat>
#include <cstdint>

#define B_  64
#define T_  1024
#define D_  128
#define NE  512            // clip limit; emb has NE+1 = 513 rows
#define P_  (B_*T_)        // 65536 positions

// d_out flat offsets (float32), in reference return order
#define O_KH   0
#define O_ENC  (P_*D_)             // 8388608
#define O_V    (O_ENC + P_)        // 8454144
#define O_LH   (O_V + 1)           // 8454145
#define O_LN   (O_LH + P_)         // 8519681
#define O_EM   (O_LN + P_)         // 8585217
#define O_LED  (O_EM + 1)          // 8585218

typedef __attribute__((ext_vector_type(8))) short bf16x8;
typedef __attribute__((ext_vector_type(4))) float floatx4;

// hi = truncate-to-bf16(x), lo = truncate-to-bf16(x - hi); pack 8 floats ->
// two uint4 (8 bf16 each, k-ascending little-endian)
__device__ __forceinline__ void pack8(const float4& a, const float4& b,
                                      uint4& h, uint4& l)
{
    float v[8] = {a.x,a.y,a.z,a.w,b.x,b.y,b.z,b.w};
    unsigned hw[4], lw[4];
    #pragma unroll
    for (int e = 0; e < 4; e++) {
        const unsigned ua = __float_as_uint(v[2*e]);
        const unsigned ub = __float_as_uint(v[2*e+1]);
        const float fa = __uint_as_float(ua & 0xffff0000u);
        const float fb = __uint_as_float(ub & 0xffff0000u);
        const unsigned da = __float_as_uint(v[2*e]   - fa);
        const unsigned db = __float_as_uint(v[2*e+1] - fb);
        hw[e] = (ub & 0xffff0000u) | (ua >> 16);
        lw[e] = (db & 0xffff0000u) | (da >> 16);
    }
    h = make_uint4(hw[0],hw[1],hw[2],hw[3]);
    l = make_uint4(lw[0],lw[1],lw[2],lw[3]);
}

__device__ __forceinline__ unsigned long long shflx64(unsigned long long v, int d)
{
    const int lo = __shfl_xor((int)(unsigned)(v & 0xffffffffULL), d);
    const int hi = __shfl_xor((int)(unsigned)(v >> 32), d);
    return ((unsigned long long)(unsigned)hi << 32) | (unsigned)lo;
}

// ---------------------------------------------------------------------------
// kE: sq[n] = ||emb_n||^2 for n = 0..512 (wave per row)
// ---------------------------------------------------------------------------
__global__ __launch_bounds__(256) void kE(const float* __restrict__ emb,
                                          float* __restrict__ sq)
{
    const int w = threadIdx.x >> 6, lane = threadIdx.x & 63;
    const int r = blockIdx.x * 4 + w;
    if (r > 512) return;
    const float2 e = ((const float2*)(emb + (size_t)r * D_))[lane];
    float s = e.x*e.x + e.y*e.y;
    #pragma unroll
    for (int m = 32; m >= 1; m >>= 1) s += __shfl_xor(s, m);
    if (lane == 0) sq[r] = s;
}

// ---------------------------------------------------------------------------
// kF: pre-convert emb (rows 0..511) to bf16 hi/lo in MFMA A-frag layout.
// ---------------------------------------------------------------------------
__global__ __launch_bounds__(256) void kF(const float* __restrict__ emb,
                                          unsigned short* __restrict__ ehi,
                                          unsigned short* __restrict__ elo)
{
    const int t = blockIdx.x * 256 + threadIdx.x;     // 0..2047
    const int n = t >> 2, kst = t & 3;
    const float4* src = (const float4*)(emb + (size_t)n * D_ + kst * 32);
    #pragma unroll
    for (int q = 0; q < 4; q++) {
        uint4 h, l;
        pack8(src[2*q], src[2*q+1], h, l);
        const size_t f = ((size_t)(n >> 4) * 4 + kst) * 4 + q;
        *(uint4*)(ehi + f*128 + (size_t)(n & 15)*8) = h;
        *(uint4*)(elo + f*128 + (size_t)(n & 15)*8) = l;
    }
}

// ---------------------------------------------------------------------------
// kA: transposed MFMA GEMM (M = n, N = p). Pass 1 computes S, stay-bit words
// (bit63 left 0), chunk argmins, and chunk-first S into LDS sF. Pass 2 (after
// barrier) patches bit63 = (chunk-last S <= next chunk's first S) -- chunk 7
// forced stay (n=511 clip) -- and stores final 64-bit words. bits are FINAL;
// kB needs no patching.
// ---------------------------------------------------------------------------
__global__ __launch_bounds__(256) void kA(const float* __restrict__ ks,
                                          const float* __restrict__ sq,
                                          const unsigned short* __restrict__ ehi,
                                          const unsigned short* __restrict__ elo,
                                          unsigned long long* __restrict__ bits,
                                          float* __restrict__ minv,
                                          int* __restrict__ mini)
{
    __shared__ unsigned short Bhi[16*64*8];   // 16 KB: [kq][p_local][8]
    __shared__ unsigned short Blo[16*64*8];   // 16 KB
    __shared__ float sF[8][64];               // chunk-first S per (chunk, p)

    const int tid  = threadIdx.x;
    const int lane = tid & 63;
    const int wv   = tid >> 6;
    const int m    = lane & 15;               // p within 16-tile
    const int q    = lane >> 4;               // quad
    const int p0   = blockIdx.x * 64;

    // ---- stage ks tile (64 p x 128 k) as bf16 hi/lo frags ----
    {
        const int row = tid >> 2;             // p_local 0..63
        const int kh  = tid & 3;              // k-quarter (32 k)
        const float4* src = (const float4*)(ks + (size_t)(p0 + row) * D_ + kh * 32);
        #pragma unroll
        for (int g = 0; g < 4; g++) {
            uint4 h, l;
            pack8(src[2*g], src[2*g+1], h, l);
            const int kq = kh*4 + g;
            *(uint4*)&Bhi[(kq*64 + row)*8] = h;
            *(uint4*)&Blo[(kq*64 + row)*8] = l;
        }
    }
    __syncthreads();

    unsigned long long wsave[2][4];
    float s33save[2][4];

    for (int cc = 0; cc < 2; cc++) {
        const int ch = wv + cc*4;             // chunk 0..7
        const int nb = ch * 64;               // chunk base n

        floatx4 acc[4][4];
        #pragma unroll
        for (int i = 0; i < 4; i++)
            #pragma unroll
            for (int j = 0; j < 4; j++)
                #pragma unroll
                for (int r = 0; r < 4; r++) acc[i][j][r] = 0.f;

        #pragma unroll 1
        for (int kst = 0; kst < 4; kst++) {
            bf16x8 ah[4], al[4], bh[4], bl[4];
            #pragma unroll
            for (int i = 0; i < 4; i++) {
                const size_t f = ((size_t)(ch*4 + i) * 4 + kst) * 4 + q;
                ah[i] = *(const bf16x8*)(ehi + f*128 + (size_t)m*8);
                al[i] = *(const bf16x8*)(elo + f*128 + (size_t)m*8);
            }
            const int kq = kst*4 + q;
            #pragma unroll
            for (int j = 0; j < 4; j++) {
                bh[j] = *(const bf16x8*)&Bhi[(kq*64 + j*16 + m)*8];
                bl[j] = *(const bf16x8*)&Blo[(kq*64 + j*16 + m)*8];
            }
            #pragma unroll
            for (int i = 0; i < 4; i++)
                #pragma unroll
                for (int j = 0; j < 4; j++)
                    acc[i][j] = __builtin_amdgcn_mfma_f32_16x16x32_bf16(ah[i], bh[j], acc[i][j], 0, 0, 0);
            #pragma unroll
            for (int i = 0; i < 4; i++)
                #pragma unroll
                for (int j = 0; j < 4; j++)
                    acc[i][j] = __builtin_amdgcn_mfma_f32_16x16x32_bf16(ah[i], bl[j], acc[i][j], 0, 0, 0);
            #pragma unroll
            for (int i = 0; i < 4; i++)
                #pragma unroll
                for (int j = 0; j < 4; j++)
                    acc[i][j] = __builtin_amdgcn_mfma_f32_16x16x32_bf16(al[i], bh[j], acc[i][j], 0, 0, 0);
        }

        // ---- epilogue pass 1 ----
        float sa[4][4];
        #pragma unroll
        for (int i = 0; i < 4; i++) {
            const float4 s4 = *(const float4*)(sq + nb + i*16 + q*4);
            sa[i][0]=s4.x; sa[i][1]=s4.y; sa[i][2]=s4.z; sa[i][3]=s4.w;
        }
        #pragma unroll
        for (int j = 0; j < 4; j++) {
            float S[4][4];
            #pragma unroll
            for (int i = 0; i < 4; i++)
                #pragma unroll
                for (int r = 0; r < 4; r++)
                    S[i][r] = fmaf(-2.f, acc[i][j][r], sa[i][r]);

            // neighbor S at quad/tile boundaries
            float nq[4], ni[4];
            #pragma unroll
            for (int i = 0; i < 4; i++) nq[i] = __shfl_down(S[i][0], 16);
            #pragma unroll
            for (int i = 0; i < 3; i++) ni[i] = __shfl(S[i+1][0], m);
            ni[3] = 0.f;

            unsigned long long w = 0;
            #pragma unroll
            for (int i = 0; i < 4; i++) {
                #pragma unroll
                for (int r = 0; r < 3; r++)
                    w |= (unsigned long long)(S[i][r] <= S[i][r+1]) << (16*i + 4*q + r);
                if (!(i == 3 && q == 3)) {     // bit63 patched in pass 2
                    const float nxt = (q < 3) ? nq[i] : ni[i];
                    w |= (unsigned long long)(S[i][3] <= nxt) << (16*i + 4*q + 3);
                }
            }
            w |= shflx64(w, 16);
            w |= shflx64(w, 32);
            wsave[cc][j]   = w;
            s33save[cc][j] = S[3][3];          // chunk-last S (valid at q==3)
            if (q == 0) sF[ch][j*16 + m] = S[0][0];

            // chunk argmin (first-index tie-break)
            float mv = S[0][0]; int mi_ = nb + q*4;
            #pragma unroll
            for (int i = 0; i < 4; i++)
                #pragma unroll
                for (int r = 0; r < 4; r++) {
                    if (i == 0 && r == 0) continue;
                    const int nid = nb + 16*i + 4*q + r;
                    if (S[i][r] < mv) { mv = S[i][r]; mi_ = nid; }
                }
            #pragma unroll
            for (int d = 16; d <= 32; d <<= 1) {
                const float v2 = __shfl_xor(mv, d);
                const int   i2 = __shfl_xor(mi_, d);
                if (v2 < mv || (v2 == mv && i2 < mi_)) { mv = v2; mi_ = i2; }
            }
            const size_t pg = (size_t)(p0 + j*16 + m);
            if (q == 0) {
                minv[pg*8 + ch] = mv;
                mini[pg*8 + ch] = mi_;
            }
        }
    }
    __syncthreads();

    // ---- epilogue pass 2: patch bit63, store final words ----
    #pragma unroll
    for (int cc = 0; cc < 2; cc++) {
        const int ch = wv + cc*4;
        #pragma unroll
        for (int j = 0; j < 4; j++) {
            const float s33 = __shfl(s33save[cc][j], 48 + m);   // from q==3 lane
            bool b63 = true;                                     // chunk 7: n=511 clip -> stay
            if (ch < 7) b63 = (s33 <= sF[ch+1][j*16 + m]);
            const unsigned long long w = wsave[cc][j]
                                       | ((unsigned long long)b63 << 63);
            const size_t pg = (size_t)(p0 + j*16 + m);
            if (q == 0) bits[pg*8 + ch] = w;
        }
    }
}

// ---------------------------------------------------------------------------
// kB: one wave per b. ind0 from global argmin at t=0, then 16 windows of 64
// scan steps. The walk state is wave-uniform: each window, lane j pre-loads
// and pre-shifts the 64-bit stay window [cur0, cur0+63] for t0+j from global
// bits, and the 64 steps run fully unrolled with v_readlane (scalar pipe, no
// LDS, no shuffles in the dependency chain).
// ---------------------------------------------------------------------------
__global__ __launch_bounds__(64) void kB(const float* __restrict__ ks,
                                         const float* __restrict__ emb,
                                         const unsigned char* __restrict__ mask,
                                         const unsigned long long* __restrict__ bits,
                                         const float* __restrict__ minv,
                                         const int* __restrict__ mini,
                                         int* __restrict__ enci,
                                         float* __restrict__ out)
{
    const int b    = blockIdx.x;
    const int lane = threadIdx.x;
    const size_t p0 = (size_t)b * T_;

    // ind0: combine 8 chunk partials + S[512]
    const float2 e = ((const float2*)(emb + (size_t)512*D_))[lane];
    const float2 k = ((const float2*)(ks  + p0*D_))[lane];
    float s5 = e.x*(e.x - 2.f*k.x) + e.y*(e.y - 2.f*k.y);
    #pragma unroll
    for (int m = 32; m >= 1; m >>= 1) s5 += __shfl_xor(s5, m);

    float mv; int mi;
    if (lane < 8)       { mv = minv[p0*8 + lane]; mi = mini[p0*8 + lane]; }
    else if (lane == 8) { mv = s5; mi = 512; }
    else                { mv = FLT_MAX; mi = 0x7fffffff; }
    #pragma unroll
    for (int m = 32; m >= 1; m >>= 1) {
        float v2 = __shfl_xor(mv, m);
        int   i2 = __shfl_xor(mi, m);
        if (v2 < mv || (v2 == mv && i2 < mi)) { mv = v2; mi = i2; }
    }
    int cur = (mi < NE) ? mi : NE - 1;
    if (mask[b]) cur = 0;
    if (lane == 0) { enci[p0] = cur; out[O_ENC + p0] = (float)cur; }

    for (int t0 = 1; t0 < T_; t0 += 64) {
        const int w0   = cur >> 6;
        const int off0 = cur & 63;
        const int t    = t0 + lane;
        unsigned long long u = ~0ULL;          // garbage lanes: stay (no advance)
        if (t < T_) {
            const size_t base = (p0 + t) * 8;
            const unsigned long long a  = bits[base + w0];
            const unsigned long long b2 = (w0 < 7) ? bits[base + w0 + 1] : ~0ULL;
            u = (off0 == 0) ? a : ((a >> off0) | (b2 << (64 - off0)));
        }
        const unsigned ulo = (unsigned)u;
        const unsigned uhi = (unsigned)(u >> 32);

        int doff = 0;                           // cur - cur0, wave-uniform
        int myenc = cur;
        #pragma unroll
        for (int j = 0; j < 64; j++) {
            const unsigned slo = (unsigned)__builtin_amdgcn_readlane((int)ulo, j);
            const unsigned shi = (unsigned)__builtin_amdgcn_readlane((int)uhi, j);
            const unsigned long long word = ((unsigned long long)shi << 32) | slo;
            const int bit = (int)((word >> doff) & 1ULL);
            doff += 1 - bit;
            if (lane == j) myenc = cur + doff;
        }
        cur += doff;
        if (t < T_) {
            enci[p0 + t] = myenc;
            out[O_ENC + p0 + t] = (float)myenc;
        }
    }
}

// ---------------------------------------------------------------------------
// kC: one wave per position. Recompute S at {enc, enc+1, 512, argmin} via
// fp32 wave dot-products; emit key_hard, loss_here, loss_next, energy.
// ---------------------------------------------------------------------------
__global__ __launch_bounds__(256) void kC(const float* __restrict__ ks,
                                          const float* __restrict__ emb,
                                          const int* __restrict__ enci,
                                          const float* __restrict__ minv,
                                          const int* __restrict__ mini,
                                          float* __restrict__ out,
                                          float* __restrict__ energy)
{
    const int lane = threadIdx.x & 63;
    const size_t p = (size_t)blockIdx.x * 4 + (threadIdx.x >> 6);

    const float2 k  = ((const float2*)(ks + p*D_))[lane];
    const int eh = enci[p];
    const int en = (eh + 1 < NE) ? eh + 1 : NE - 1;
    const float2 Eh = ((const float2*)(emb + (size_t)eh*D_))[lane];
    const float2 En = ((const float2*)(emb + (size_t)en*D_))[lane];
    const float2 E5 = ((const float2*)(emb + (size_t)512*D_))[lane];

    float ph  = Eh.x*(Eh.x - 2.f*k.x) + Eh.y*(Eh.y - 2.f*k.y);
    float pn  = En.x*(En.x - 2.f*k.x) + En.y*(En.y - 2.f*k.y);
    float p5  = E5.x*(E5.x - 2.f*k.x) + E5.y*(E5.y - 2.f*k.y);
    float sqk = k.x*k.x + k.y*k.y;
    #pragma unroll
    for (int m = 32; m >= 1; m >>= 1) {
        ph  += __shfl_xor(ph, m);
        pn  += __shfl_xor(pn, m);
        p5  += __shfl_xor(p5, m);
        sqk += __shfl_xor(sqk, m);
    }

    float mv; int mi;
    if (lane < 8)       { mv = minv[p*8 + lane]; mi = mini[p*8 + lane]; }
    else if (lane == 8) { mv = p5; mi = 512; }
    else                { mv = FLT_MAX; mi = 0x7fffffff; }
    #pragma unroll
    for (int m = 32; m >= 1; m >>= 1) {
        float v2 = __shfl_xor(mv, m);
        int   i2 = __shfl_xor(mi, m);
        if (v2 < mv || (v2 == mv && i2 < mi)) { mv = v2; mi = i2; }
    }

    const float2 Em = ((const float2*)(emb + (size_t)mi*D_))[lane];
    float pm = Em.x*(Em.x - 2.f*k.x) + Em.y*(Em.y - 2.f*k.y);
    #pragma unroll
    for (int m = 32; m >= 1; m >>= 1) pm += __shfl_xor(pm, m);

    const float lh = 1.2f * (sqk + ph);
    const float ln = 1.2f * (sqk + pn);
    const float lm = 1.2f * (sqk + pm);
    const float lossh = lh - ln - ((pm < ph) ? lm : 0.f);
    const float lossn = ln - lh - ((pm < pn) ? lm : 0.f);

    float2 kh;
    kh.x = k.x + (Eh.x - k.x);
    kh.y = k.y + (Eh.y - k.y);
    ((float2*)(out + p*D_))[lane] = kh;

    if (lane == 0) {
        out[O_LH + p] = lossh;
        out[O_LN + p] = lossn;
        energy[p] = 1.2f * (pn - ph);
    }
}

// ---------------------------------------------------------------------------
// kD1: per-256-position partial sums (energy, energy-descent terms)
// ---------------------------------------------------------------------------
__global__ __launch_bounds__(256) void kD1(const float* __restrict__ energy,
                                           const int* __restrict__ enci,
                                           double2* __restrict__ part)
{
    __shared__ double sA[256], sB[256];
    const int p = blockIdx.x * 256 + threadIdx.x;
    const float e = energy[p];
    double se = (double)e;
    double sl = 0.0;
    if ((p & (T_-1)) < T_-1) {
        const float ec = (enci[p+1] == enci[p]) ? (energy[p+1] - e) : 0.f;
        sl = (double)fmaxf(ec + (float)(1e-6/512.0), 0.f);
    }
    sA[threadIdx.x] = se; sB[threadIdx.x] = sl;
    __syncthreads();
    for (int s = 128; s >= 1; s >>= 1) {
        if (threadIdx.x < (unsigned)s) {
            sA[threadIdx.x] += sA[threadIdx.x+s];
            sB[threadIdx.x] += sB[threadIdx.x+s];
        }
        __syncthreads();
    }
    if (threadIdx.x == 0) { part[blockIdx.x] = make_double2(sA[0], sB[0]); }
}

// ---------------------------------------------------------------------------
// kD2: final reduce of 256 partials + v = max over b of (enc_last - enc_first)
// ---------------------------------------------------------------------------
__global__ __launch_bounds__(256) void kD2(const double2* __restrict__ part,
                                           const int* __restrict__ enci,
                                           float* __restrict__ out)
{
    __shared__ double sA[256], sB[256];
    const double2 pv = part[threadIdx.x];
    sA[threadIdx.x] = pv.x; sB[threadIdx.x] = pv.y;
    __syncthreads();
    for (int s = 128; s >= 1; s >>= 1) {
        if (threadIdx.x < (unsigned)s) {
            sA[threadIdx.x] += sA[threadIdx.x+s];
            sB[threadIdx.x] += sB[threadIdx.x+s];
        }
        __syncthreads();
    }
    if (threadIdx.x < 64) {
        int v = enci[(size_t)threadIdx.x*T_ + T_-1] - enci[(size_t)threadIdx.x*T_];
        #pragma unroll
        for (int m = 32; m >= 1; m >>= 1) {
            const int v2 = __shfl_xor(v, m);
            v = (v2 > v) ? v2 : v;
        }
        if (threadIdx.x == 0) {
            out[O_V]   = (float)v;
            out[O_EM]  = (float)(sA[0] / (double)P_);
            out[O_LED] = (float)(sB[0] / (double)(B_*(T_-1)));
        }
    }
}

// ---------------------------------------------------------------------------
extern "C" void kernel_launch(void* const* d_in, const int* in_sizes, int n_in,
                              void* d_out, int out_size, void* d_ws, size_t ws_size,
                              hipStream_t stream)
{
    const float* ks  = (const float*)d_in[0];
    const float* emb = (const float*)d_in[1];
    const unsigned char* mask = (const unsigned char*)d_in[2];

    float* out = (float*)d_out;
    char* w = (char*)d_ws;
    unsigned long long* bits = (unsigned long long*)(w);                      // 4 MB
    float* minv   = (float*)(w + (size_t) 8*1024*1024);                       // 2 MB
    int*   mini   = (int*)  (w + (size_t)10*1024*1024);                       // 2 MB
    int*   enci   = (int*)  (w + (size_t)12*1024*1024);                       // 256 KB
    float* energy = (float*)(w + (size_t)12*1024*1024 + 256*1024);            // 256 KB
    float* sq     = (float*)(w + (size_t)12*1024*1024 + 512*1024);            // 4 KB
    double2* part = (double2*)(w + (size_t)12*1024*1024 + 516*1024);          // 4 KB
    unsigned short* ehi = (unsigned short*)(w + (size_t)12*1024*1024 + 640*1024); // 128 KB
    unsigned short* elo = (unsigned short*)(w + (size_t)12*1024*1024 + 768*1024); // 128 KB

    kE <<<129,  256, 0, stream>>>(emb, sq);
    kF <<<8,    256, 0, stream>>>(emb, ehi, elo);
    kA <<<1024, 256, 0, stream>>>(ks, sq, ehi, elo, bits, minv, mini);
    kB <<<B_,   64,  0, stream>>>(ks, emb, mask, bits, minv, mini, enci, out);
    kC <<<P_/4, 256, 0, stream>>>(ks, emb, enci, minv, mini, out, energy);
    kD1<<<256,  256, 0, stream>>>(energy, enci, part);
    kD2<<<1,    256, 0, stream>>>(part, enci, out);
}

// Round 6
// 197.151 us; speedup vs baseline: 4.6199x; 1.0879x over previous
//
#include <hip/hip_runtime.h>
#include <cfloat>
#include <cstdint>

#define B_  64
#define T_  1024
#define D_  128
#define NE  512            // clip limit; emb has NE+1 = 513 rows
#define P_  (B_*T_)        // 65536 positions

// d_out flat offsets (float32), in reference return order
#define O_KH   0
#define O_ENC  (P_*D_)             // 8388608
#define O_V    (O_ENC + P_)        // 8454144
#define O_LH   (O_V + 1)           // 8454145
#define O_LN   (O_LH + P_)         // 8519681
#define O_EM   (O_LN + P_)         // 8585217
#define O_LED  (O_EM + 1)          // 8585218

typedef __attribute__((ext_vector_type(8))) short bf16x8;
typedef __attribute__((ext_vector_type(4))) float floatx4;
typedef unsigned long long u64;

// hi = truncate-to-bf16(x), lo = truncate-to-bf16(x - hi); pack 8 floats ->
// two uint4 (8 bf16 each, k-ascending little-endian)
__device__ __forceinline__ void pack8(const float4& a, const float4& b,
                                      uint4& h, uint4& l)
{
    float v[8] = {a.x,a.y,a.z,a.w,b.x,b.y,b.z,b.w};
    unsigned hw[4], lw[4];
    #pragma unroll
    for (int e = 0; e < 4; e++) {
        const unsigned ua = __float_as_uint(v[2*e]);
        const unsigned ub = __float_as_uint(v[2*e+1]);
        const float fa = __uint_as_float(ua & 0xffff0000u);
        const float fb = __uint_as_float(ub & 0xffff0000u);
        const unsigned da = __float_as_uint(v[2*e]   - fa);
        const unsigned db = __float_as_uint(v[2*e+1] - fb);
        hw[e] = (ub & 0xffff0000u) | (ua >> 16);
        lw[e] = (db & 0xffff0000u) | (da >> 16);
    }
    h = make_uint4(hw[0],hw[1],hw[2],hw[3]);
    l = make_uint4(lw[0],lw[1],lw[2],lw[3]);
}

__device__ __forceinline__ u64 shflx64(u64 v, int d)
{
    const int lo = __shfl_xor((int)(unsigned)(v & 0xffffffffULL), d);
    const int hi = __shfl_xor((int)(unsigned)(v >> 32), d);
    return ((u64)(unsigned)hi << 32) | (unsigned)lo;
}

// ---------------------------------------------------------------------------
// kF: pre-convert emb (rows 0..511) to bf16 hi/lo in MFMA A-frag layout AND
// compute sq[n] = ||emb_n||^2 (quad shuffle reduce). sq[512] is never used
// downstream (kB/kC compute S[512] locally).
// ---------------------------------------------------------------------------
__global__ __launch_bounds__(256) void kF(const float* __restrict__ emb,
                                          unsigned short* __restrict__ ehi,
                                          unsigned short* __restrict__ elo,
                                          float* __restrict__ sq)
{
    const int t = blockIdx.x * 256 + threadIdx.x;     // 0..2047
    const int n = t >> 2, kst = t & 3;
    const float4* src = (const float4*)(emb + (size_t)n * D_ + kst * 32);
    float ss = 0.f;
    #pragma unroll
    for (int g = 0; g < 4; g++) {
        const float4 a = src[2*g], b = src[2*g+1];
        ss += a.x*a.x + a.y*a.y + a.z*a.z + a.w*a.w
            + b.x*b.x + b.y*b.y + b.z*b.z + b.w*b.w;
        uint4 h, l;
        pack8(a, b, h, l);
        const int f = ((n >> 4) * 4 + kst) * 4 + g;
        *(uint4*)(ehi + (size_t)f*128 + (size_t)(n & 15)*8) = h;
        *(uint4*)(elo + (size_t)f*128 + (size_t)(n & 15)*8) = l;
    }
    ss += __shfl_xor(ss, 1);
    ss += __shfl_xor(ss, 2);
    if (kst == 0) sq[n] = ss;
}

// ---------------------------------------------------------------------------
// kA: transposed MFMA GEMM (M = n, N = p), ONE chunk (64 n) per wave.
// grid 2048 = 1024 p-tiles x 2 chunk-halves; wave wv -> chunk half*4+wv.
// B (ks tile, 64 p x 128 k) staged once to LDS as bf16 hi/lo frags; A (emb)
// frags from kF's global arrays (L2-resident). hi/lo 3-pass MFMA.
// Outputs: bits (bit63 = 0 except chunk 7 = 1/clip; boundaries patched in
// kB), sfirst/slast chunk-edge S, chunk argmin (minv/mini).
// ---------------------------------------------------------------------------
__global__ __launch_bounds__(256) void kA(const float* __restrict__ ks,
                                          const float* __restrict__ sq,
                                          const unsigned short* __restrict__ ehi,
                                          const unsigned short* __restrict__ elo,
                                          u64* __restrict__ bits,
                                          float* __restrict__ sfirst,
                                          float* __restrict__ slast,
                                          float* __restrict__ minv,
                                          int* __restrict__ mini)
{
    __shared__ unsigned short Bhi[16*64*8];   // 16 KB: [kq][p_local][8]
    __shared__ unsigned short Blo[16*64*8];   // 16 KB

    const int tid  = threadIdx.x;
    const int lane = tid & 63;
    const int wv   = tid >> 6;
    const int m    = lane & 15;               // p within 16-tile
    const int q    = lane >> 4;               // quad
    const int p0   = (blockIdx.x >> 1) * 64;
    const int ch   = (blockIdx.x & 1) * 4 + wv;   // chunk 0..7
    const int nb   = ch * 64;

    // ---- stage ks tile (64 p x 128 k) as bf16 hi/lo frags ----
    {
        const int row = tid >> 2;             // p_local 0..63
        const int kh  = tid & 3;              // k-quarter (32 k)
        const float4* src = (const float4*)(ks + (size_t)(p0 + row) * D_ + kh * 32);
        #pragma unroll
        for (int g = 0; g < 4; g++) {
            uint4 h, l;
            pack8(src[2*g], src[2*g+1], h, l);
            const int kq = kh*4 + g;
            *(uint4*)&Bhi[(kq*64 + row)*8] = h;
            *(uint4*)&Blo[(kq*64 + row)*8] = l;
        }
    }
    __syncthreads();

    floatx4 acc[4][4];
    #pragma unroll
    for (int i = 0; i < 4; i++)
        #pragma unroll
        for (int j = 0; j < 4; j++)
            #pragma unroll
            for (int r = 0; r < 4; r++) acc[i][j][r] = 0.f;

    #pragma unroll 1
    for (int kst = 0; kst < 4; kst++) {
        bf16x8 ah[4], al[4], bh[4], bl[4];
        #pragma unroll
        for (int i = 0; i < 4; i++) {
            const int f = ((ch*4 + i) * 4 + kst) * 4 + q;   // n-tile frag slot
            const int off = f*128 + m*8;
            ah[i] = *(const bf16x8*)(ehi + off);
            al[i] = *(const bf16x8*)(elo + off);
        }
        const int kq = kst*4 + q;
        #pragma unroll
        for (int j = 0; j < 4; j++) {
            bh[j] = *(const bf16x8*)&Bhi[(kq*64 + j*16 + m)*8];
            bl[j] = *(const bf16x8*)&Blo[(kq*64 + j*16 + m)*8];
        }
        #pragma unroll
        for (int i = 0; i < 4; i++)
            #pragma unroll
            for (int j = 0; j < 4; j++)
                acc[i][j] = __builtin_amdgcn_mfma_f32_16x16x32_bf16(ah[i], bh[j], acc[i][j], 0, 0, 0);
        #pragma unroll
        for (int i = 0; i < 4; i++)
            #pragma unroll
            for (int j = 0; j < 4; j++)
                acc[i][j] = __builtin_amdgcn_mfma_f32_16x16x32_bf16(ah[i], bl[j], acc[i][j], 0, 0, 0);
        #pragma unroll
        for (int i = 0; i < 4; i++)
            #pragma unroll
            for (int j = 0; j < 4; j++)
                acc[i][j] = __builtin_amdgcn_mfma_f32_16x16x32_bf16(al[i], bh[j], acc[i][j], 0, 0, 0);
    }

    // ---- epilogue (register-local; bit63 of non-terminal chunks patched in kB) ----
    float sa[4][4];
    #pragma unroll
    for (int i = 0; i < 4; i++) {
        const float4 s4 = *(const float4*)(sq + nb + i*16 + q*4);
        sa[i][0]=s4.x; sa[i][1]=s4.y; sa[i][2]=s4.z; sa[i][3]=s4.w;
    }
    #pragma unroll
    for (int j = 0; j < 4; j++) {
        float S[4][4];
        #pragma unroll
        for (int i = 0; i < 4; i++)
            #pragma unroll
            for (int r = 0; r < 4; r++)
                S[i][r] = fmaf(-2.f, acc[i][j][r], sa[i][r]);

        // neighbor S at quad/tile boundaries
        float nq[4], ni[4];
        #pragma unroll
        for (int i = 0; i < 4; i++) nq[i] = __shfl_down(S[i][0], 16);
        #pragma unroll
        for (int i = 0; i < 3; i++) ni[i] = __shfl(S[i+1][0], m);
        ni[3] = 0.f;

        u64 w = 0;
        #pragma unroll
        for (int i = 0; i < 4; i++) {
            #pragma unroll
            for (int r = 0; r < 3; r++)
                w |= (u64)(S[i][r] <= S[i][r+1]) << (16*i + 4*q + r);
            if (!(i == 3 && q == 3)) {
                const float nxt = (q < 3) ? nq[i] : ni[i];
                w |= (u64)(S[i][3] <= nxt) << (16*i + 4*q + 3);
            }
        }
        if (ch == 7 && q == 3) w |= 1ULL << 63;   // n=511 clip -> stay
        w |= shflx64(w, 16);
        w |= shflx64(w, 32);

        // chunk argmin (first-index tie-break)
        float mv = S[0][0]; int mi_ = nb + q*4;
        #pragma unroll
        for (int i = 0; i < 4; i++)
            #pragma unroll
            for (int r = 0; r < 4; r++) {
                if (i == 0 && r == 0) continue;
                const int nid = nb + 16*i + 4*q + r;
                if (S[i][r] < mv) { mv = S[i][r]; mi_ = nid; }
            }
        #pragma unroll
        for (int d = 16; d <= 32; d <<= 1) {
            const float v2 = __shfl_xor(mv, d);
            const int   i2 = __shfl_xor(mi_, d);
            if (v2 < mv || (v2 == mv && i2 < mi_)) { mv = v2; mi_ = i2; }
        }

        const size_t pg = (size_t)(p0 + j*16 + m);
        if (q == 0) {
            bits  [pg*8 + ch] = w;
            sfirst[pg*8 + ch] = S[0][0];
            minv  [pg*8 + ch] = mv;
            mini  [pg*8 + ch] = mi_;
        }
        if (q == 3) slast[pg*8 + ch] = S[3][3];
    }
}

// ---------------------------------------------------------------------------
// kB: one wave per b. ind0 from global argmin at t=0, then 16 windows of 64
// scan steps. Per window, lane j pre-loads (one window AHEAD, double-
// buffered) the full 8-word bits row + sfirst/slast rows for t0+j, patches
// all 7 chunk-boundary bit63s in registers, selects the window words by the
// wave-uniform w0 (cndmask chain), and runs 64 fully-unrolled readlane scan
// steps (scalar pipe, no LDS, no dependent loads at window start).
// ---------------------------------------------------------------------------
struct KBwin { u64 W[8]; float F[8]; float L[8]; };

__global__ __launch_bounds__(64) void kB(const float* __restrict__ ks,
                                         const float* __restrict__ emb,
                                         const unsigned char* __restrict__ mask,
                                         const u64* __restrict__ bits,
                                         const float* __restrict__ sfirst,
                                         const float* __restrict__ slast,
                                         const float* __restrict__ minv,
                                         const int* __restrict__ mini,
                                         int* __restrict__ enci,
                                         float* __restrict__ out)
{
    const int b    = blockIdx.x;
    const int lane = threadIdx.x;
    const size_t p0 = (size_t)b * T_;

    // ind0: combine 8 chunk partials + S[512]
    const float2 e = ((const float2*)(emb + (size_t)512*D_))[lane];
    const float2 k = ((const float2*)(ks  + p0*D_))[lane];
    float s5 = e.x*(e.x - 2.f*k.x) + e.y*(e.y - 2.f*k.y);
    #pragma unroll
    for (int m = 32; m >= 1; m >>= 1) s5 += __shfl_xor(s5, m);

    float mv; int mi;
    if (lane < 8)       { mv = minv[p0*8 + lane]; mi = mini[p0*8 + lane]; }
    else if (lane == 8) { mv = s5; mi = 512; }
    else                { mv = FLT_MAX; mi = 0x7fffffff; }
    #pragma unroll
    for (int m = 32; m >= 1; m >>= 1) {
        float v2 = __shfl_xor(mv, m);
        int   i2 = __shfl_xor(mi, m);
        if (v2 < mv || (v2 == mv && i2 < mi)) { mv = v2; mi = i2; }
    }
    int cur = (mi < NE) ? mi : NE - 1;
    if (mask[b]) cur = 0;
    if (lane == 0) { enci[p0] = cur; out[O_ENC + p0] = (float)cur; }

    KBwin wa, wb;

    auto loadwin = [&](KBwin& d, int t0) {
        const int t = t0 + lane;
        if (t < T_) {
            const ulonglong2* bp = (const ulonglong2*)(bits + (p0 + t)*8);
            const ulonglong2 w01 = bp[0], w23 = bp[1], w45 = bp[2], w67 = bp[3];
            d.W[0]=w01.x; d.W[1]=w01.y; d.W[2]=w23.x; d.W[3]=w23.y;
            d.W[4]=w45.x; d.W[5]=w45.y; d.W[6]=w67.x; d.W[7]=w67.y;
            const float4* fp = (const float4*)(sfirst + (p0 + t)*8);
            const float4 f0 = fp[0], f1 = fp[1];
            d.F[0]=f0.x; d.F[1]=f0.y; d.F[2]=f0.z; d.F[3]=f0.w;
            d.F[4]=f1.x; d.F[5]=f1.y; d.F[6]=f1.z; d.F[7]=f1.w;
            const float4* lp = (const float4*)(slast + (p0 + t)*8);
            const float4 l0 = lp[0], l1 = lp[1];
            d.L[0]=l0.x; d.L[1]=l0.y; d.L[2]=l0.z; d.L[3]=l0.w;
            d.L[4]=l1.x; d.L[5]=l1.y; d.L[6]=l1.z; d.L[7]=l1.w;
        } else {
            #pragma unroll
            for (int c = 0; c < 8; c++) { d.W[c] = ~0ULL; d.F[c] = 1.f; d.L[c] = 0.f; }
        }
    };

    auto scanwin = [&](KBwin& d, int t0) {
        // patch chunk-boundary stay bits
        #pragma unroll
        for (int c = 0; c < 7; c++)
            d.W[c] |= (u64)(d.L[c] <= d.F[c+1]) << 63;

        const int w0   = cur >> 6;
        const int off0 = cur & 63;
        u64 a = d.W[0];
        #pragma unroll
        for (int c = 1; c < 8; c++) a = (w0 == c) ? d.W[c] : a;
        u64 bn = ~0ULL;
        #pragma unroll
        for (int c = 1; c < 8; c++) bn = (w0 == c-1) ? d.W[c] : bn;
        const u64 u = (off0 == 0) ? a : ((a >> off0) | (bn << (64 - off0)));

        const unsigned ulo = (unsigned)u;
        const unsigned uhi = (unsigned)(u >> 32);
        int doff = 0;
        int myenc = cur;
        #pragma unroll
        for (int j = 0; j < 64; j++) {
            const unsigned slo = (unsigned)__builtin_amdgcn_readlane((int)ulo, j);
            const unsigned shi = (unsigned)__builtin_amdgcn_readlane((int)uhi, j);
            const u64 word = ((u64)shi << 32) | slo;
            const int bit = (int)((word >> doff) & 1ULL);
            doff += 1 - bit;
            if (lane == j) myenc = cur + doff;
        }
        cur += doff;
        const int t = t0 + lane;
        if (t < T_) {
            enci[p0 + t] = myenc;
            out[O_ENC + p0 + t] = (float)myenc;
        }
    };

    loadwin(wa, 1);
    #pragma unroll 1
    for (int wp = 0; wp < 8; wp++) {
        const int t0a = 1 + wp*128;
        loadwin(wb, t0a + 64);
        scanwin(wa, t0a);
        if (wp < 7) loadwin(wa, t0a + 128);
        scanwin(wb, t0a + 64);
    }
}

// ---------------------------------------------------------------------------
// kC: one wave per position. Recompute S at {enc, enc+1, 512, argmin} via
// fp32 wave dot-products; emit key_hard, loss_here, loss_next, energy.
// ---------------------------------------------------------------------------
__global__ __launch_bounds__(256) void kC(const float* __restrict__ ks,
                                          const float* __restrict__ emb,
                                          const int* __restrict__ enci,
                                          const float* __restrict__ minv,
                                          const int* __restrict__ mini,
                                          float* __restrict__ out,
                                          float* __restrict__ energy)
{
    const int lane = threadIdx.x & 63;
    const size_t p = (size_t)blockIdx.x * 4 + (threadIdx.x >> 6);

    const float2 k  = ((const float2*)(ks + p*D_))[lane];
    const int eh = enci[p];
    const int en = (eh + 1 < NE) ? eh + 1 : NE - 1;
    const float2 Eh = ((const float2*)(emb + (size_t)eh*D_))[lane];
    const float2 En = ((const float2*)(emb + (size_t)en*D_))[lane];
    const float2 E5 = ((const float2*)(emb + (size_t)512*D_))[lane];

    float ph  = Eh.x*(Eh.x - 2.f*k.x) + Eh.y*(Eh.y - 2.f*k.y);
    float pn  = En.x*(En.x - 2.f*k.x) + En.y*(En.y - 2.f*k.y);
    float p5  = E5.x*(E5.x - 2.f*k.x) + E5.y*(E5.y - 2.f*k.y);
    float sqk = k.x*k.x + k.y*k.y;
    #pragma unroll
    for (int m = 32; m >= 1; m >>= 1) {
        ph  += __shfl_xor(ph, m);
        pn  += __shfl_xor(pn, m);
        p5  += __shfl_xor(p5, m);
        sqk += __shfl_xor(sqk, m);
    }

    float mv; int mi;
    if (lane < 8)       { mv = minv[p*8 + lane]; mi = mini[p*8 + lane]; }
    else if (lane == 8) { mv = p5; mi = 512; }
    else                { mv = FLT_MAX; mi = 0x7fffffff; }
    #pragma unroll
    for (int m = 32; m >= 1; m >>= 1) {
        float v2 = __shfl_xor(mv, m);
        int   i2 = __shfl_xor(mi, m);
        if (v2 < mv || (v2 == mv && i2 < mi)) { mv = v2; mi = i2; }
    }

    const float2 Em = ((const float2*)(emb + (size_t)mi*D_))[lane];
    float pm = Em.x*(Em.x - 2.f*k.x) + Em.y*(Em.y - 2.f*k.y);
    #pragma unroll
    for (int m = 32; m >= 1; m >>= 1) pm += __shfl_xor(pm, m);

    const float lh = 1.2f * (sqk + ph);
    const float ln = 1.2f * (sqk + pn);
    const float lm = 1.2f * (sqk + pm);
    const float lossh = lh - ln - ((pm < ph) ? lm : 0.f);
    const float lossn = ln - lh - ((pm < pn) ? lm : 0.f);

    float2 kh;
    kh.x = k.x + (Eh.x - k.x);
    kh.y = k.y + (Eh.y - k.y);
    ((float2*)(out + p*D_))[lane] = kh;

    if (lane == 0) {
        out[O_LH + p] = lossh;
        out[O_LN + p] = lossn;
        energy[p] = 1.2f * (pn - ph);
    }
}

// ---------------------------------------------------------------------------
// kD1: per-256-position partial sums (energy, energy-descent terms)
// ---------------------------------------------------------------------------
__global__ __launch_bounds__(256) void kD1(const float* __restrict__ energy,
                                           const int* __restrict__ enci,
                                           double2* __restrict__ part)
{
    __shared__ double sA[256], sB[256];
    const int p = blockIdx.x * 256 + threadIdx.x;
    const float e = energy[p];
    double se = (double)e;
    double sl = 0.0;
    if ((p & (T_-1)) < T_-1) {
        const float ec = (enci[p+1] == enci[p]) ? (energy[p+1] - e) : 0.f;
        sl = (double)fmaxf(ec + (float)(1e-6/512.0), 0.f);
    }
    sA[threadIdx.x] = se; sB[threadIdx.x] = sl;
    __syncthreads();
    for (int s = 128; s >= 1; s >>= 1) {
        if (threadIdx.x < (unsigned)s) {
            sA[threadIdx.x] += sA[threadIdx.x+s];
            sB[threadIdx.x] += sB[threadIdx.x+s];
        }
        __syncthreads();
    }
    if (threadIdx.x == 0) { part[blockIdx.x] = make_double2(sA[0], sB[0]); }
}

// ---------------------------------------------------------------------------
// kD2: final reduce of 256 partials + v = max over b of (enc_last - enc_first)
// ---------------------------------------------------------------------------
__global__ __launch_bounds__(256) void kD2(const double2* __restrict__ part,
                                           const int* __restrict__ enci,
                                           float* __restrict__ out)
{
    __shared__ double sA[256], sB[256];
    const double2 pv = part[threadIdx.x];
    sA[threadIdx.x] = pv.x; sB[threadIdx.x] = pv.y;
    __syncthreads();
    for (int s = 128; s >= 1; s >>= 1) {
        if (threadIdx.x < (unsigned)s) {
            sA[threadIdx.x] += sA[threadIdx.x+s];
            sB[threadIdx.x] += sB[threadIdx.x+s];
        }
        __syncthreads();
    }
    if (threadIdx.x < 64) {
        int v = enci[(size_t)threadIdx.x*T_ + T_-1] - enci[(size_t)threadIdx.x*T_];
        #pragma unroll
        for (int m = 32; m >= 1; m >>= 1) {
            const int v2 = __shfl_xor(v, m);
            v = (v2 > v) ? v2 : v;
        }
        if (threadIdx.x == 0) {
            out[O_V]   = (float)v;
            out[O_EM]  = (float)(sA[0] / (double)P_);
            out[O_LED] = (float)(sB[0] / (double)(B_*(T_-1)));
        }
    }
}

// ---------------------------------------------------------------------------
extern "C" void kernel_launch(void* const* d_in, const int* in_sizes, int n_in,
                              void* d_out, int out_size, void* d_ws, size_t ws_size,
                              hipStream_t stream)
{
    const float* ks  = (const float*)d_in[0];
    const float* emb = (const float*)d_in[1];
    const unsigned char* mask = (const unsigned char*)d_in[2];

    float* out = (float*)d_out;
    char* w = (char*)d_ws;
    u64*   bits   = (u64*)  (w);                                              // 4 MB
    float* sfirst = (float*)(w + (size_t) 4*1024*1024);                       // 2 MB
    float* slast  = (float*)(w + (size_t) 6*1024*1024);                       // 2 MB
    float* minv   = (float*)(w + (size_t) 8*1024*1024);                       // 2 MB
    int*   mini   = (int*)  (w + (size_t)10*1024*1024);                       // 2 MB
    int*   enci   = (int*)  (w + (size_t)12*1024*1024);                       // 256 KB
    float* energy = (float*)(w + (size_t)12*1024*1024 + 256*1024);            // 256 KB
    float* sq     = (float*)(w + (size_t)12*1024*1024 + 512*1024);            // 4 KB
    double2* part = (double2*)(w + (size_t)12*1024*1024 + 516*1024);          // 4 KB
    unsigned short* ehi = (unsigned short*)(w + (size_t)12*1024*1024 + 640*1024); // 128 KB
    unsigned short* elo = (unsigned short*)(w + (size_t)12*1024*1024 + 768*1024); // 128 KB

    kF <<<8,    256, 0, stream>>>(emb, ehi, elo, sq);
    kA <<<2048, 256, 0, stream>>>(ks, sq, ehi, elo, bits, sfirst, slast, minv, mini);
    kB <<<B_,   64,  0, stream>>>(ks, emb, mask, bits, sfirst, slast, minv, mini, enci, out);
    kC <<<P_/4, 256, 0, stream>>>(ks, emb, enci, minv, mini, out, energy);
    kD1<<<256,  256, 0, stream>>>(energy, enci, part);
    kD2<<<1,    256, 0, stream>>>(part, enci, out);
}